// Round 8
// baseline (380.466 us; speedup 1.0000x reference)
//
#include <hip/hip_runtime.h>
#include <hip/hip_bf16.h>

typedef __attribute__((ext_vector_type(4))) float f32x4;
typedef __attribute__((ext_vector_type(8))) short bf16x8;
typedef __attribute__((ext_vector_type(8))) unsigned short u16x8;

#define QCAP 8256  // compact q buffer row capacity (8192 + tail headroom)

__device__ __forceinline__ unsigned short f2bf(float f) {
  unsigned int u = __builtin_bit_cast(unsigned int, f);
  unsigned int r = (u + 0x7FFFu + ((u >> 16) & 1u)) >> 16;
  return (unsigned short)r;
}
__device__ __forceinline__ float bf2f(unsigned short h) {
  unsigned int u = ((unsigned int)h) << 16;
  return __builtin_bit_cast(float, u);
}

__device__ __forceinline__ void gload_lds16(const void* g, void* l) {
  __builtin_amdgcn_global_load_lds(
      (__attribute__((address_space(1))) unsigned int*)g,
      (__attribute__((address_space(3))) unsigned int*)l, 16, 0, 0);
}

// ---------- fp32 -> bf16 bulk convert (dense; used for latent) ----------
__global__ __launch_bounds__(256) void cvt_bf16(const float* __restrict__ in,
                                                unsigned short* __restrict__ out,
                                                long n) {
  long i = ((long)blockIdx.x * 256 + threadIdx.x) * 8;
  if (i >= n) return;
  f32x4 a = *(const f32x4*)(in + i);
  f32x4 b = *(const f32x4*)(in + i + 4);
  u16x8 o;
#pragma unroll
  for (int j = 0; j < 4; ++j) o[j] = f2bf(a[j]);
#pragma unroll
  for (int j = 0; j < 4; ++j) o[4 + j] = f2bf(b[j]);
  *(u16x8*)(out + i) = o;
}

// ---------- gathered fp32 -> bf16 convert for y (compact valid rows) ----------
// block pair per compact row p: half of 4096 cols each (256 thr x 8 elems)
__global__ __launch_bounds__(256) void cvt_gather(
    const float* __restrict__ y, const int* __restrict__ glob,
    const int* __restrict__ offs, unsigned short* __restrict__ ybf) {
  int p = blockIdx.x >> 1, half = blockIdx.x & 1;
  if (p >= offs[12]) return;
  int g = glob[p];
  const float* src = y + (size_t)g * 4096 + half * 2048 + threadIdx.x * 8;
  unsigned short* dst = ybf + (size_t)p * 4096 + half * 2048 + threadIdx.x * 8;
  f32x4 a = *(const f32x4*)src;
  f32x4 b = *(const f32x4*)(src + 4);
  u16x8 o;
#pragma unroll
  for (int j = 0; j < 4; ++j) o[j] = f2bf(a[j]);
#pragma unroll
  for (int j = 0; j < 4; ++j) o[4 + j] = f2bf(b[j]);
  *(u16x8*)dst = o;
}

// ---------- weight transpose + hi/lo split ----------
__global__ __launch_bounds__(256) void transpose_split(
    const float* __restrict__ W, unsigned short* __restrict__ Th,
    unsigned short* __restrict__ Tl, int K, int N) {
  __shared__ float tile[32][33];
  int n0 = blockIdx.x * 32, k0 = blockIdx.y * 32;
  int tx = threadIdx.x, ty = threadIdx.y;  // (32, 8)
#pragma unroll
  for (int r = 0; r < 4; ++r)
    tile[ty + 8 * r][tx] = W[(size_t)(k0 + ty + 8 * r) * N + n0 + tx];
  __syncthreads();
#pragma unroll
  for (int r = 0; r < 4; ++r) {
    float f = tile[tx][ty + 8 * r];
    unsigned short hi = f2bf(f);
    unsigned short lo = f2bf(f - bf2f(hi));
    size_t o = (size_t)(n0 + ty + 8 * r) * K + k0 + tx;
    Th[o] = hi;
    Tl[o] = lo;
  }
}

// ---------- gather rows by (b, t); also collect masked rows ----------
__global__ __launch_bounds__(256) void gather_rows(const int* __restrict__ mask,
                                                   int* __restrict__ cnt,
                                                   int* __restrict__ idx,
                                                   int* __restrict__ mcnt,
                                                   int* __restrict__ mlist) {
  int g = blockIdx.x * 256 + threadIdx.x;  // 0..8191
  int m = mask[g];
  if (m > 0) {
    int bt = (g >> 11) * 3 + m - 1;
    int p = atomicAdd(&cnt[bt], 1);
    idx[bt * 2048 + p] = g;
  } else {
    int p = atomicAdd(mcnt, 1);
    mlist[p] = g;
  }
}

// ---------- exclusive scan of 12 bucket counts ----------
__global__ void scan_offsets(const int* __restrict__ cnt, int* __restrict__ offs) {
  if (threadIdx.x == 0) {
    int s = 0;
#pragma unroll
    for (int i = 0; i < 12; ++i) {
      offs[i] = s;
      s += cnt[i];
    }
    offs[12] = s;
  }
}

// ---------- build bucket-major global compact list ----------
__global__ __launch_bounds__(256) void build_glob(const int* __restrict__ cnt,
                                                  const int* __restrict__ offs,
                                                  const int* __restrict__ idx,
                                                  int* __restrict__ glob) {
  int bt = blockIdx.x;
  int n = cnt[bt], o = offs[bt];
  for (int j = threadIdx.x; j < n; j += 256) glob[o + j] = idx[bt * 2048 + j];
}

// ---------- zero-fill out rows for masked queries ----------
__global__ __launch_bounds__(256) void zerofill(const int* __restrict__ mcnt,
                                                const int* __restrict__ mlist,
                                                float* __restrict__ out) {
  int w = blockIdx.x * 4 + (threadIdx.x >> 6);
  int lane = threadIdx.x & 63;
  if (w >= *mcnt) return;
  float* row = out + (size_t)mlist[w] * 4096;
  f32x4 z = (f32x4){0.f, 0.f, 0.f, 0.f};
#pragma unroll
  for (int i = 0; i < 16; ++i) *(f32x4*)(row + i * 256 + lane * 4) = z;
}

// ---------- bf16x2 / bf16 GEMM ----------
// EPI 1: fp32 split-K partial into [KSL][M(stride)][N], early-exit past offs[12]
// EPI 2: kv epilogue -> Kh/Kl bf16 [bt][h][key][d], Vt bf16 [bt][h][d][key]
// EPI 3: fp32 row-scatter via glob, guarded by offs[12]
#define BM 128
#define BN 128
#define BK 64

template <int EPI, int KSL, bool USE_BL>
__global__ __launch_bounds__(256) void gemm2(
    const unsigned short* __restrict__ A, const unsigned short* __restrict__ Bh,
    const unsigned short* __restrict__ Bl, void* __restrict__ Cv,
    void* __restrict__ Cv2, void* __restrict__ Cv3,
    const int* __restrict__ glob, const int* __restrict__ offs, int M, int N,
    int K) {
  __shared__ unsigned short Ald[BM * BK];
  __shared__ unsigned short Bhld[BN * BK];
  __shared__ unsigned short Blld[USE_BL ? BN * BK : 64];
  int tid = threadIdx.x, lane = tid & 63, wid = tid >> 6;
  int wr = wid >> 1, wc = wid & 1;
  // bijective XCD swizzle (nwg % 8 == 0 for all uses)
  int nwg = gridDim.x;
  int w = (blockIdx.x & 7) * (nwg >> 3) + (blockIdx.x >> 3);
  int nTN = N / BN;
  int bm, bn, ks;
  if constexpr (KSL == 1) {
    bm = w / nTN;
    bn = w % nTN;
    ks = 0;
  } else {
    bm = w / (nTN * KSL);
    int r = w % (nTN * KSL);
    bn = r / KSL;
    ks = r % KSL;
  }
  int mv = M;
  if constexpr (EPI == 1 || EPI == 3) mv = offs[12];
  if (bm * BM >= mv) return;  // block-uniform early exit (no barriers yet)

  int kbeg = ks * (K / KSL), kend = kbeg + K / KSL;
  const unsigned short* Ab = A + (size_t)(bm * BM) * K;
  const unsigned short* Bhb = Bh + (size_t)(bn * BN) * K;
  const unsigned short* Blb = USE_BL ? Bl + (size_t)(bn * BN) * K : nullptr;
  int fr = lane & 15, fq = lane >> 4;
  int srow = lane >> 3, scol = (lane & 7) * 8;

  f32x4 acc[4][4];
#pragma unroll
  for (int i = 0; i < 4; ++i)
#pragma unroll
    for (int j = 0; j < 4; ++j) acc[i][j] = (f32x4){0.f, 0.f, 0.f, 0.f};

  for (int k0 = kbeg; k0 < kend; k0 += BK) {
#pragma unroll
    for (int i = 0; i < 4; ++i) {
      int c = wid * 4 + i;
      size_t go = (size_t)(c * 8 + srow) * K + k0 + scol;
      gload_lds16(Ab + go, &Ald[c * 512]);
      gload_lds16(Bhb + go, &Bhld[c * 512]);
      if constexpr (USE_BL) gload_lds16(Blb + go, &Blld[c * 512]);
    }
    __syncthreads();
#pragma unroll
    for (int kk = 0; kk < 2; ++kk) {
      bf16x8 af[4], bhf[4], blf[4];
#pragma unroll
      for (int i = 0; i < 4; ++i) {
        af[i] = *(const bf16x8*)&Ald[(wr * 64 + i * 16 + fr) * BK + kk * 32 + fq * 8];
        bhf[i] = *(const bf16x8*)&Bhld[(wc * 64 + i * 16 + fr) * BK + kk * 32 + fq * 8];
        if constexpr (USE_BL)
          blf[i] = *(const bf16x8*)&Blld[(wc * 64 + i * 16 + fr) * BK + kk * 32 + fq * 8];
      }
#pragma unroll
      for (int mi = 0; mi < 4; ++mi)
#pragma unroll
        for (int ni = 0; ni < 4; ++ni) {
          acc[mi][ni] = __builtin_amdgcn_mfma_f32_16x16x32_bf16(
              af[mi], bhf[ni], acc[mi][ni], 0, 0, 0);
          if constexpr (USE_BL)
            acc[mi][ni] = __builtin_amdgcn_mfma_f32_16x16x32_bf16(
                af[mi], blf[ni], acc[mi][ni], 0, 0, 0);
        }
    }
    __syncthreads();
  }

#pragma unroll
  for (int mi = 0; mi < 4; ++mi)
#pragma unroll
    for (int ni = 0; ni < 4; ++ni)
#pragma unroll
      for (int r = 0; r < 4; ++r) {
        int row = bm * BM + wr * 64 + mi * 16 + fq * 4 + r;
        int col = bn * BN + wc * 64 + ni * 16 + fr;
        if constexpr (EPI == 1) {
          ((float*)Cv)[(size_t)ks * M * N + (size_t)row * N + col] =
              acc[mi][ni][r];
        } else if constexpr (EPI == 2) {  // kv epilogue
          int bt = row >> 6, key = row & 63;
          float v = acc[mi][ni][r];
          if (col < 512) {
            int h = col >> 6, d = col & 63;
            unsigned short hi = f2bf(v);
            unsigned short lo = f2bf(v - bf2f(hi));
            size_t o = ((size_t)(bt * 8 + h) * 64 + key) * 64 + d;
            ((unsigned short*)Cv)[o] = hi;   // Kh
            ((unsigned short*)Cv2)[o] = lo;  // Kl
          } else {
            int c = col - 512;
            int h = c >> 6, d = c & 63;
            ((unsigned short*)Cv3)[((size_t)(bt * 8 + h) * 64 + d) * 64 + key] =
                f2bf(v);  // Vt
          }
        } else {  // EPI == 3: guarded row scatter
          if (row < mv)
            ((float*)Cv)[(size_t)glob[row] * N + col] = acc[mi][ni][r];
        }
      }
}

// ---------- MFMA attention (compact positions) ----------
// block = (bucket bt, 32-row tile rt); 4 waves, wave handles heads 2w,2w+1.
__global__ __launch_bounds__(256) void attn5(
    const float* __restrict__ q0, const float* __restrict__ q1,
    const unsigned short* __restrict__ Kh, const unsigned short* __restrict__ Kl,
    const unsigned short* __restrict__ Vt, const int* __restrict__ cnt,
    const int* __restrict__ offs, unsigned short* __restrict__ attnc) {
  __shared__ unsigned short Pl[4][32][72];
  int tid = threadIdx.x, wid = tid >> 6, lane = tid & 63;
  int fr = lane & 15, fq = lane >> 4;
  int bt = blockIdx.x >> 6, rt = blockIdx.x & 63;
  int n = cnt[bt];
  int rbase = rt * 32;
  if (rbase >= n) return;
  int qbase = offs[bt] + rbase;  // compact position of local row 0

#pragma unroll 1
  for (int hp = 0; hp < 2; ++hp) {
    int h = wid * 2 + hp;
    const unsigned short* khb = Kh + ((size_t)(bt * 8 + h) * 64) * 64;
    const unsigned short* klb = Kl + ((size_t)(bt * 8 + h) * 64) * 64;
    const unsigned short* vtb = Vt + ((size_t)(bt * 8 + h) * 64) * 64;

    f32x4 sacc[2][4];
#pragma unroll
    for (int i = 0; i < 2; ++i)
#pragma unroll
      for (int j = 0; j < 4; ++j) sacc[i][j] = (f32x4){0.f, 0.f, 0.f, 0.f};

#pragma unroll
    for (int kk = 0; kk < 2; ++kk) {
      bf16x8 qh[2], ql[2];
#pragma unroll
      for (int mi = 0; mi < 2; ++mi) {
        size_t qo = (size_t)(qbase + mi * 16 + fr) * 512 + h * 64 + kk * 32 + fq * 8;
        f32x4 a0 = *(const f32x4*)(q0 + qo);
        f32x4 a1 = *(const f32x4*)(q0 + qo + 4);
        f32x4 b0 = *(const f32x4*)(q1 + qo);
        f32x4 b1 = *(const f32x4*)(q1 + qo + 4);
        float sv[8];
        *(f32x4*)&sv[0] = a0 + b0;
        *(f32x4*)&sv[4] = a1 + b1;
#pragma unroll
        for (int j = 0; j < 8; ++j) {
          unsigned short hi = f2bf(sv[j]);
          qh[mi][j] = (short)hi;
          ql[mi][j] = (short)f2bf(sv[j] - bf2f(hi));
        }
      }
#pragma unroll
      for (int ni = 0; ni < 4; ++ni) {
        size_t ko = (size_t)(ni * 16 + fr) * 64 + kk * 32 + fq * 8;
        bf16x8 kh = *(const bf16x8*)(khb + ko);
        bf16x8 kl = *(const bf16x8*)(klb + ko);
#pragma unroll
        for (int mi = 0; mi < 2; ++mi) {
          sacc[mi][ni] = __builtin_amdgcn_mfma_f32_16x16x32_bf16(
              qh[mi], kh, sacc[mi][ni], 0, 0, 0);
          sacc[mi][ni] = __builtin_amdgcn_mfma_f32_16x16x32_bf16(
              qh[mi], kl, sacc[mi][ni], 0, 0, 0);
          sacc[mi][ni] = __builtin_amdgcn_mfma_f32_16x16x32_bf16(
              ql[mi], kh, sacc[mi][ni], 0, 0, 0);
        }
      }
    }

    // softmax over keys: lane holds rows {mi*16+fq*4+r}, cols {ni*16+fr}
#pragma unroll
    for (int mi = 0; mi < 2; ++mi) {
#pragma unroll
      for (int r = 0; r < 4; ++r) {
        float m = fmaxf(fmaxf(sacc[mi][0][r], sacc[mi][1][r]),
                        fmaxf(sacc[mi][2][r], sacc[mi][3][r]));
#pragma unroll
        for (int o = 1; o < 16; o <<= 1) m = fmaxf(m, __shfl_xor(m, o));
        float e0 = __expf(sacc[mi][0][r] - m);
        float e1 = __expf(sacc[mi][1][r] - m);
        float e2 = __expf(sacc[mi][2][r] - m);
        float e3 = __expf(sacc[mi][3][r] - m);
        float s = e0 + e1 + e2 + e3;
#pragma unroll
        for (int o = 1; o < 16; o <<= 1) s += __shfl_xor(s, o);
        float inv = 1.f / s;
        int row = mi * 16 + fq * 4 + r;
        Pl[wid][row][fr] = f2bf(e0 * inv);
        Pl[wid][row][16 + fr] = f2bf(e1 * inv);
        Pl[wid][row][32 + fr] = f2bf(e2 * inv);
        Pl[wid][row][48 + fr] = f2bf(e3 * inv);
      }
    }

    // O = P · Vt
    f32x4 oacc[2][4];
#pragma unroll
    for (int i = 0; i < 2; ++i)
#pragma unroll
      for (int j = 0; j < 4; ++j) oacc[i][j] = (f32x4){0.f, 0.f, 0.f, 0.f};
#pragma unroll
    for (int kk = 0; kk < 2; ++kk) {
      bf16x8 pa[2];
#pragma unroll
      for (int mi = 0; mi < 2; ++mi)
        pa[mi] = *(const bf16x8*)&Pl[wid][mi * 16 + fr][kk * 32 + fq * 8];
#pragma unroll
      for (int ni = 0; ni < 4; ++ni) {
        bf16x8 vb = *(const bf16x8*)(vtb + (size_t)(ni * 16 + fr) * 64 +
                                     kk * 32 + fq * 8);
#pragma unroll
        for (int mi = 0; mi < 2; ++mi)
          oacc[mi][ni] = __builtin_amdgcn_mfma_f32_16x16x32_bf16(
              pa[mi], vb, oacc[mi][ni], 0, 0, 0);
      }
    }

    // store to compact attn buffer
#pragma unroll
    for (int mi = 0; mi < 2; ++mi)
#pragma unroll
      for (int r = 0; r < 4; ++r) {
        int row = mi * 16 + fq * 4 + r;
        if (rbase + row < n) {
          unsigned short* ar = attnc + (size_t)(qbase + row) * 512 + h * 64 + fr;
          ar[0] = f2bf(oacc[mi][0][r]);
          ar[16] = f2bf(oacc[mi][1][r]);
          ar[32] = f2bf(oacc[mi][2][r]);
          ar[48] = f2bf(oacc[mi][3][r]);
        }
      }
  }
}

// ---------- launch ----------
extern "C" void kernel_launch(void* const* d_in, const int* in_sizes, int n_in,
                              void* d_out, int out_size, void* d_ws,
                              size_t ws_size, hipStream_t stream) {
  const float* latent = (const float*)d_in[0];
  const float* y = (const float*)d_in[1];
  const int* mask = (const int*)d_in[2];
  const float* W_vk = (const float*)d_in[3];
  const float* W_q = (const float*)d_in[4];
  const float* W_out = (const float*)d_in[5];
  float* out = (float*)d_out;

  char* ws = (char*)d_ws;
  size_t off = 0;
  auto alloc = [&](size_t bytes) -> void* {
    void* p = ws + off;
    off = (off + bytes + 255) & ~(size_t)255;
    return p;
  };
  unsigned short* WqT_h = (unsigned short*)alloc((size_t)512 * 4096 * 2);
  unsigned short* WqT_l = (unsigned short*)alloc((size_t)512 * 4096 * 2);
  unsigned short* WvkT_h = (unsigned short*)alloc((size_t)1024 * 2048 * 2);
  unsigned short* WvkT_l = (unsigned short*)alloc((size_t)1024 * 2048 * 2);
  unsigned short* WoT_h = (unsigned short*)alloc((size_t)4096 * 512 * 2);
  unsigned short* WoT_l = (unsigned short*)alloc((size_t)4096 * 512 * 2);
  unsigned short* ybf = (unsigned short*)alloc((size_t)8192 * 4096 * 2);
  unsigned short* latbf = (unsigned short*)alloc((size_t)768 * 2048 * 2);
  float* qc = (float*)alloc((size_t)2 * QCAP * 512 * 4);  // compact split-K q
  unsigned short* Khb = (unsigned short*)alloc((size_t)768 * 512 * 2);
  unsigned short* Klb = (unsigned short*)alloc((size_t)768 * 512 * 2);
  unsigned short* Vtb = (unsigned short*)alloc((size_t)768 * 512 * 2);
  unsigned short* attnc = (unsigned short*)alloc((size_t)8192 * 512 * 2);
  int* cnt = (int*)alloc(12 * 4);
  int* idx = (int*)alloc((size_t)12 * 2048 * 4);
  int* offs = (int*)alloc(13 * 4);
  int* glob = (int*)alloc(8192 * 4);
  int* mcnt = (int*)alloc(4);
  int* mlist = (int*)alloc(8192 * 4);

  hipMemsetAsync(cnt, 0, 12 * 4, stream);
  hipMemsetAsync(mcnt, 0, 4, stream);
  hipMemsetAsync(glob, 0, 8192 * 4, stream);

  cvt_bf16<<<768, 256, 0, stream>>>(latent, latbf, (long)768 * 2048);

  dim3 tb(32, 8);
  transpose_split<<<dim3(16, 128), tb, 0, stream>>>(W_q, WqT_h, WqT_l, 4096, 512);
  transpose_split<<<dim3(32, 64), tb, 0, stream>>>(W_vk, WvkT_h, WvkT_l, 2048, 1024);
  transpose_split<<<dim3(128, 16), tb, 0, stream>>>(W_out, WoT_h, WoT_l, 512, 4096);

  gather_rows<<<32, 256, 0, stream>>>(mask, cnt, idx, mcnt, mlist);
  scan_offsets<<<1, 64, 0, stream>>>(cnt, offs);
  build_glob<<<12, 256, 0, stream>>>(cnt, offs, idx, glob);
  zerofill<<<2048, 256, 0, stream>>>(mcnt, mlist, out);

  // compact y -> bf16 (valid rows only)
  cvt_gather<<<16384, 256, 0, stream>>>(y, glob, offs, ybf);

  // kv = latent[768,2048] @ W_vk ; epilogue -> Kh/Kl, Vt
  gemm2<2, 1, true><<<(768 / BM) * (1024 / BN), 256, 0, stream>>>(
      latbf, WvkT_h, WvkT_l, Khb, Klb, Vtb, nullptr, nullptr, 768, 1024, 2048);
  // q = ybf[compact,4096] @ W_q -> fp32 split-K partials (2 slices), stride QCAP
  gemm2<1, 2, true><<<(8192 / BM) * (512 / BN) * 2, 256, 0, stream>>>(
      ybf, WqT_h, WqT_l, qc, nullptr, nullptr, nullptr, offs, QCAP, 512, 4096);
  // MFMA attention on compact positions
  attn5<<<12 * 64, 256, 0, stream>>>(qc, qc + (size_t)QCAP * 512, Khb, Klb,
                                     Vtb, cnt, offs, attnc);
  // out = attnc[compact,512] @ W_out (single-bf16 B) -> scatter fp32 rows
  gemm2<3, 1, false><<<(8192 / BM) * (4096 / BN), 256, 0, stream>>>(
      attnc, WoT_h, nullptr, out, nullptr, nullptr, glob, offs, 8192, 4096, 512);
}

// Round 9
// 362.111 us; speedup vs baseline: 1.0507x; 1.0507x over previous
//
#include <hip/hip_runtime.h>
#include <hip/hip_bf16.h>

typedef __attribute__((ext_vector_type(4))) float f32x4;
typedef __attribute__((ext_vector_type(8))) short bf16x8;
typedef __attribute__((ext_vector_type(8))) unsigned short u16x8;

#define QCAP 8256  // compact q buffer row capacity (8192 + tail headroom)

__device__ __forceinline__ unsigned short f2bf(float f) {
  unsigned int u = __builtin_bit_cast(unsigned int, f);
  unsigned int r = (u + 0x7FFFu + ((u >> 16) & 1u)) >> 16;
  return (unsigned short)r;
}
__device__ __forceinline__ float bf2f(unsigned short h) {
  unsigned int u = ((unsigned int)h) << 16;
  return __builtin_bit_cast(float, u);
}

__device__ __forceinline__ void gload_lds16(const void* g, void* l) {
  __builtin_amdgcn_global_load_lds(
      (__attribute__((address_space(1))) unsigned int*)g,
      (__attribute__((address_space(3))) unsigned int*)l, 16, 0, 0);
}

// ---------- fp32 -> bf16 bulk convert (dense; used for latent) ----------
__global__ __launch_bounds__(256) void cvt_bf16(const float* __restrict__ in,
                                                unsigned short* __restrict__ out,
                                                long n) {
  long i = ((long)blockIdx.x * 256 + threadIdx.x) * 8;
  if (i >= n) return;
  f32x4 a = *(const f32x4*)(in + i);
  f32x4 b = *(const f32x4*)(in + i + 4);
  u16x8 o;
#pragma unroll
  for (int j = 0; j < 4; ++j) o[j] = f2bf(a[j]);
#pragma unroll
  for (int j = 0; j < 4; ++j) o[4 + j] = f2bf(b[j]);
  *(u16x8*)(out + i) = o;
}

// ---------- gathered fp32 -> bf16 convert for y (compact valid rows) ----------
__global__ __launch_bounds__(256) void cvt_gather(
    const float* __restrict__ y, const int* __restrict__ glob,
    const int* __restrict__ offs, unsigned short* __restrict__ ybf) {
  int p = blockIdx.x >> 1, half = blockIdx.x & 1;
  if (p >= offs[12]) return;
  int g = glob[p];
  const float* src = y + (size_t)g * 4096 + half * 2048 + threadIdx.x * 8;
  unsigned short* dst = ybf + (size_t)p * 4096 + half * 2048 + threadIdx.x * 8;
  f32x4 a = *(const f32x4*)src;
  f32x4 b = *(const f32x4*)(src + 4);
  u16x8 o;
#pragma unroll
  for (int j = 0; j < 4; ++j) o[j] = f2bf(a[j]);
#pragma unroll
  for (int j = 0; j < 4; ++j) o[4 + j] = f2bf(b[j]);
  *(u16x8*)dst = o;
}

// ---------- weight transpose + hi/lo split ----------
__global__ __launch_bounds__(256) void transpose_split(
    const float* __restrict__ W, unsigned short* __restrict__ Th,
    unsigned short* __restrict__ Tl, int K, int N) {
  __shared__ float tile[32][33];
  int n0 = blockIdx.x * 32, k0 = blockIdx.y * 32;
  int tx = threadIdx.x, ty = threadIdx.y;  // (32, 8)
#pragma unroll
  for (int r = 0; r < 4; ++r)
    tile[ty + 8 * r][tx] = W[(size_t)(k0 + ty + 8 * r) * N + n0 + tx];
  __syncthreads();
#pragma unroll
  for (int r = 0; r < 4; ++r) {
    float f = tile[tx][ty + 8 * r];
    unsigned short hi = f2bf(f);
    unsigned short lo = f2bf(f - bf2f(hi));
    size_t o = (size_t)(n0 + ty + 8 * r) * K + k0 + tx;
    Th[o] = hi;
    Tl[o] = lo;
  }
}

// ---------- gather rows by (b, t); also collect masked rows ----------
__global__ __launch_bounds__(256) void gather_rows(const int* __restrict__ mask,
                                                   int* __restrict__ cnt,
                                                   int* __restrict__ idx,
                                                   int* __restrict__ mcnt,
                                                   int* __restrict__ mlist) {
  int g = blockIdx.x * 256 + threadIdx.x;  // 0..8191
  int m = mask[g];
  if (m > 0) {
    int bt = (g >> 11) * 3 + m - 1;
    int p = atomicAdd(&cnt[bt], 1);
    idx[bt * 2048 + p] = g;
  } else {
    int p = atomicAdd(mcnt, 1);
    mlist[p] = g;
  }
}

// ---------- exclusive scan of 12 bucket counts ----------
__global__ void scan_offsets(const int* __restrict__ cnt, int* __restrict__ offs) {
  if (threadIdx.x == 0) {
    int s = 0;
#pragma unroll
    for (int i = 0; i < 12; ++i) {
      offs[i] = s;
      s += cnt[i];
    }
    offs[12] = s;
  }
}

// ---------- build bucket-major global compact list ----------
__global__ __launch_bounds__(256) void build_glob(const int* __restrict__ cnt,
                                                  const int* __restrict__ offs,
                                                  const int* __restrict__ idx,
                                                  int* __restrict__ glob) {
  int bt = blockIdx.x;
  int n = cnt[bt], o = offs[bt];
  for (int j = threadIdx.x; j < n; j += 256) glob[o + j] = idx[bt * 2048 + j];
}

// ---------- zero-fill out rows for masked queries ----------
__global__ __launch_bounds__(256) void zerofill(const int* __restrict__ mcnt,
                                                const int* __restrict__ mlist,
                                                float* __restrict__ out) {
  int w = blockIdx.x * 4 + (threadIdx.x >> 6);
  int lane = threadIdx.x & 63;
  if (w >= *mcnt) return;
  float* row = out + (size_t)mlist[w] * 4096;
  f32x4 z = (f32x4){0.f, 0.f, 0.f, 0.f};
#pragma unroll
  for (int i = 0; i < 16; ++i) *(f32x4*)(row + i * 256 + lane * 4) = z;
}

// ---------- bf16x2 / bf16 GEMM with XOR-swizzled LDS ----------
// Staging: global source column pre-swizzled (rule #21) so linear
// global_load_lds dest receives swizzled layout: LDS[row][cl] holds
// global col 8*((cl/8)^(row&7)) + cl%8. Reads XOR the element col with
// (row&7)*8 -> bank group 4*(fq^(fr&7)): 8 groups x 2 lanes/bank = free.
// EPI 1: fp32 split-K partial into [KSL][M(stride)][N], early-exit past offs[12]
// EPI 2: kv epilogue -> Kh/Kl bf16 [bt][h][key][d], Vt bf16 [bt][h][d][key]
// EPI 3: fp32 row-scatter via glob, guarded by offs[12]
#define BM 128
#define BN 128
#define BK 64

template <int EPI, int KSL, bool USE_BL>
__global__ __launch_bounds__(256) void gemm2(
    const unsigned short* __restrict__ A, const unsigned short* __restrict__ Bh,
    const unsigned short* __restrict__ Bl, void* __restrict__ Cv,
    void* __restrict__ Cv2, void* __restrict__ Cv3,
    const int* __restrict__ glob, const int* __restrict__ offs, int M, int N,
    int K) {
  __shared__ unsigned short Ald[BM * BK];
  __shared__ unsigned short Bhld[BN * BK];
  __shared__ unsigned short Blld[USE_BL ? BN * BK : 64];
  int tid = threadIdx.x, lane = tid & 63, wid = tid >> 6;
  int wr = wid >> 1, wc = wid & 1;
  // bijective XCD swizzle (nwg % 8 == 0 for all uses)
  int nwg = gridDim.x;
  int w = (blockIdx.x & 7) * (nwg >> 3) + (blockIdx.x >> 3);
  int nTN = N / BN;
  int bm, bn, ks;
  if constexpr (KSL == 1) {
    bm = w / nTN;
    bn = w % nTN;
    ks = 0;
  } else {
    bm = w / (nTN * KSL);
    int r = w % (nTN * KSL);
    bn = r / KSL;
    ks = r % KSL;
  }
  int mv = M;
  if constexpr (EPI == 1 || EPI == 3) mv = offs[12];
  if (bm * BM >= mv) return;  // block-uniform early exit (no barriers yet)

  int kbeg = ks * (K / KSL), kend = kbeg + K / KSL;
  const unsigned short* Ab = A + (size_t)(bm * BM) * K;
  const unsigned short* Bhb = Bh + (size_t)(bn * BN) * K;
  const unsigned short* Blb = USE_BL ? Bl + (size_t)(bn * BN) * K : nullptr;
  int fr = lane & 15, fq = lane >> 4;
  // staging: pre-swizzled source column (see header comment)
  int srow = lane >> 3, scol = ((lane & 7) ^ (lane >> 3)) * 8;

  f32x4 acc[4][4];
#pragma unroll
  for (int i = 0; i < 4; ++i)
#pragma unroll
    for (int j = 0; j < 4; ++j) acc[i][j] = (f32x4){0.f, 0.f, 0.f, 0.f};

  for (int k0 = kbeg; k0 < kend; k0 += BK) {
#pragma unroll
    for (int i = 0; i < 4; ++i) {
      int c = wid * 4 + i;
      size_t go = (size_t)(c * 8 + srow) * K + k0 + scol;
      gload_lds16(Ab + go, &Ald[c * 512]);
      gload_lds16(Bhb + go, &Bhld[c * 512]);
      if constexpr (USE_BL) gload_lds16(Blb + go, &Blld[c * 512]);
    }
    __syncthreads();
#pragma unroll
    for (int kk = 0; kk < 2; ++kk) {
      int ca = (kk * 32 + fq * 8) ^ ((fr & 7) * 8);  // swizzled read col
      bf16x8 af[4], bhf[4], blf[4];
#pragma unroll
      for (int i = 0; i < 4; ++i) {
        af[i] = *(const bf16x8*)&Ald[(wr * 64 + i * 16 + fr) * BK + ca];
        bhf[i] = *(const bf16x8*)&Bhld[(wc * 64 + i * 16 + fr) * BK + ca];
        if constexpr (USE_BL)
          blf[i] = *(const bf16x8*)&Blld[(wc * 64 + i * 16 + fr) * BK + ca];
      }
#pragma unroll
      for (int mi = 0; mi < 4; ++mi)
#pragma unroll
        for (int ni = 0; ni < 4; ++ni) {
          acc[mi][ni] = __builtin_amdgcn_mfma_f32_16x16x32_bf16(
              af[mi], bhf[ni], acc[mi][ni], 0, 0, 0);
          if constexpr (USE_BL)
            acc[mi][ni] = __builtin_amdgcn_mfma_f32_16x16x32_bf16(
                af[mi], blf[ni], acc[mi][ni], 0, 0, 0);
        }
    }
    __syncthreads();
  }

#pragma unroll
  for (int mi = 0; mi < 4; ++mi)
#pragma unroll
    for (int ni = 0; ni < 4; ++ni)
#pragma unroll
      for (int r = 0; r < 4; ++r) {
        int row = bm * BM + wr * 64 + mi * 16 + fq * 4 + r;
        int col = bn * BN + wc * 64 + ni * 16 + fr;
        if constexpr (EPI == 1) {
          ((float*)Cv)[(size_t)ks * M * N + (size_t)row * N + col] =
              acc[mi][ni][r];
        } else if constexpr (EPI == 2) {  // kv epilogue
          int bt = row >> 6, key = row & 63;
          float v = acc[mi][ni][r];
          if (col < 512) {
            int h = col >> 6, d = col & 63;
            unsigned short hi = f2bf(v);
            unsigned short lo = f2bf(v - bf2f(hi));
            size_t o = ((size_t)(bt * 8 + h) * 64 + key) * 64 + d;
            ((unsigned short*)Cv)[o] = hi;   // Kh
            ((unsigned short*)Cv2)[o] = lo;  // Kl
          } else {
            int c = col - 512;
            int h = c >> 6, d = c & 63;
            ((unsigned short*)Cv3)[((size_t)(bt * 8 + h) * 64 + d) * 64 + key] =
                f2bf(v);  // Vt
          }
        } else {  // EPI == 3: guarded row scatter
          if (row < mv)
            ((float*)Cv)[(size_t)glob[row] * N + col] = acc[mi][ni][r];
        }
      }
}

// ---------- MFMA attention (compact positions) ----------
__global__ __launch_bounds__(256) void attn5(
    const float* __restrict__ q0, const float* __restrict__ q1,
    const unsigned short* __restrict__ Kh, const unsigned short* __restrict__ Kl,
    const unsigned short* __restrict__ Vt, const int* __restrict__ cnt,
    const int* __restrict__ offs, unsigned short* __restrict__ attnc) {
  __shared__ unsigned short Pl[4][32][72];
  int tid = threadIdx.x, wid = tid >> 6, lane = tid & 63;
  int fr = lane & 15, fq = lane >> 4;
  int bt = blockIdx.x >> 6, rt = blockIdx.x & 63;
  int n = cnt[bt];
  int rbase = rt * 32;
  if (rbase >= n) return;
  int qbase = offs[bt] + rbase;  // compact position of local row 0

#pragma unroll 1
  for (int hp = 0; hp < 2; ++hp) {
    int h = wid * 2 + hp;
    const unsigned short* khb = Kh + ((size_t)(bt * 8 + h) * 64) * 64;
    const unsigned short* klb = Kl + ((size_t)(bt * 8 + h) * 64) * 64;
    const unsigned short* vtb = Vt + ((size_t)(bt * 8 + h) * 64) * 64;

    f32x4 sacc[2][4];
#pragma unroll
    for (int i = 0; i < 2; ++i)
#pragma unroll
      for (int j = 0; j < 4; ++j) sacc[i][j] = (f32x4){0.f, 0.f, 0.f, 0.f};

#pragma unroll
    for (int kk = 0; kk < 2; ++kk) {
      bf16x8 qh[2], ql[2];
#pragma unroll
      for (int mi = 0; mi < 2; ++mi) {
        size_t qo = (size_t)(qbase + mi * 16 + fr) * 512 + h * 64 + kk * 32 + fq * 8;
        f32x4 a0 = *(const f32x4*)(q0 + qo);
        f32x4 a1 = *(const f32x4*)(q0 + qo + 4);
        f32x4 b0 = *(const f32x4*)(q1 + qo);
        f32x4 b1 = *(const f32x4*)(q1 + qo + 4);
        float sv[8];
        *(f32x4*)&sv[0] = a0 + b0;
        *(f32x4*)&sv[4] = a1 + b1;
#pragma unroll
        for (int j = 0; j < 8; ++j) {
          unsigned short hi = f2bf(sv[j]);
          qh[mi][j] = (short)hi;
          ql[mi][j] = (short)f2bf(sv[j] - bf2f(hi));
        }
      }
#pragma unroll
      for (int ni = 0; ni < 4; ++ni) {
        size_t ko = (size_t)(ni * 16 + fr) * 64 + kk * 32 + fq * 8;
        bf16x8 kh = *(const bf16x8*)(khb + ko);
        bf16x8 kl = *(const bf16x8*)(klb + ko);
#pragma unroll
        for (int mi = 0; mi < 2; ++mi) {
          sacc[mi][ni] = __builtin_amdgcn_mfma_f32_16x16x32_bf16(
              qh[mi], kh, sacc[mi][ni], 0, 0, 0);
          sacc[mi][ni] = __builtin_amdgcn_mfma_f32_16x16x32_bf16(
              qh[mi], kl, sacc[mi][ni], 0, 0, 0);
          sacc[mi][ni] = __builtin_amdgcn_mfma_f32_16x16x32_bf16(
              ql[mi], kh, sacc[mi][ni], 0, 0, 0);
        }
      }
    }

    // softmax over keys: lane holds rows {mi*16+fq*4+r}, cols {ni*16+fr}
#pragma unroll
    for (int mi = 0; mi < 2; ++mi) {
#pragma unroll
      for (int r = 0; r < 4; ++r) {
        float m = fmaxf(fmaxf(sacc[mi][0][r], sacc[mi][1][r]),
                        fmaxf(sacc[mi][2][r], sacc[mi][3][r]));
#pragma unroll
        for (int o = 1; o < 16; o <<= 1) m = fmaxf(m, __shfl_xor(m, o));
        float e0 = __expf(sacc[mi][0][r] - m);
        float e1 = __expf(sacc[mi][1][r] - m);
        float e2 = __expf(sacc[mi][2][r] - m);
        float e3 = __expf(sacc[mi][3][r] - m);
        float s = e0 + e1 + e2 + e3;
#pragma unroll
        for (int o = 1; o < 16; o <<= 1) s += __shfl_xor(s, o);
        float inv = 1.f / s;
        int row = mi * 16 + fq * 4 + r;
        Pl[wid][row][fr] = f2bf(e0 * inv);
        Pl[wid][row][16 + fr] = f2bf(e1 * inv);
        Pl[wid][row][32 + fr] = f2bf(e2 * inv);
        Pl[wid][row][48 + fr] = f2bf(e3 * inv);
      }
    }

    // O = P · Vt
    f32x4 oacc[2][4];
#pragma unroll
    for (int i = 0; i < 2; ++i)
#pragma unroll
      for (int j = 0; j < 4; ++j) oacc[i][j] = (f32x4){0.f, 0.f, 0.f, 0.f};
#pragma unroll
    for (int kk = 0; kk < 2; ++kk) {
      bf16x8 pa[2];
#pragma unroll
      for (int mi = 0; mi < 2; ++mi)
        pa[mi] = *(const bf16x8*)&Pl[wid][mi * 16 + fr][kk * 32 + fq * 8];
#pragma unroll
      for (int ni = 0; ni < 4; ++ni) {
        bf16x8 vb = *(const bf16x8*)(vtb + (size_t)(ni * 16 + fr) * 64 +
                                     kk * 32 + fq * 8);
#pragma unroll
        for (int mi = 0; mi < 2; ++mi)
          oacc[mi][ni] = __builtin_amdgcn_mfma_f32_16x16x32_bf16(
              pa[mi], vb, oacc[mi][ni], 0, 0, 0);
      }
    }

    // store to compact attn buffer
#pragma unroll
    for (int mi = 0; mi < 2; ++mi)
#pragma unroll
      for (int r = 0; r < 4; ++r) {
        int row = mi * 16 + fq * 4 + r;
        if (rbase + row < n) {
          unsigned short* ar = attnc + (size_t)(qbase + row) * 512 + h * 64 + fr;
          ar[0] = f2bf(oacc[mi][0][r]);
          ar[16] = f2bf(oacc[mi][1][r]);
          ar[32] = f2bf(oacc[mi][2][r]);
          ar[48] = f2bf(oacc[mi][3][r]);
        }
      }
  }
}

// ---------- launch ----------
extern "C" void kernel_launch(void* const* d_in, const int* in_sizes, int n_in,
                              void* d_out, int out_size, void* d_ws,
                              size_t ws_size, hipStream_t stream) {
  const float* latent = (const float*)d_in[0];
  const float* y = (const float*)d_in[1];
  const int* mask = (const int*)d_in[2];
  const float* W_vk = (const float*)d_in[3];
  const float* W_q = (const float*)d_in[4];
  const float* W_out = (const float*)d_in[5];
  float* out = (float*)d_out;

  char* ws = (char*)d_ws;
  size_t off = 0;
  auto alloc = [&](size_t bytes) -> void* {
    void* p = ws + off;
    off = (off + bytes + 255) & ~(size_t)255;
    return p;
  };
  unsigned short* WqT_h = (unsigned short*)alloc((size_t)512 * 4096 * 2);
  unsigned short* WqT_l = (unsigned short*)alloc((size_t)512 * 4096 * 2);
  unsigned short* WvkT_h = (unsigned short*)alloc((size_t)1024 * 2048 * 2);
  unsigned short* WvkT_l = (unsigned short*)alloc((size_t)1024 * 2048 * 2);
  unsigned short* WoT_h = (unsigned short*)alloc((size_t)4096 * 512 * 2);
  unsigned short* WoT_l = (unsigned short*)alloc((size_t)4096 * 512 * 2);
  unsigned short* ybf = (unsigned short*)alloc((size_t)8192 * 4096 * 2);
  unsigned short* latbf = (unsigned short*)alloc((size_t)768 * 2048 * 2);
  float* qc = (float*)alloc((size_t)2 * QCAP * 512 * 4);  // compact split-K q
  unsigned short* Khb = (unsigned short*)alloc((size_t)768 * 512 * 2);
  unsigned short* Klb = (unsigned short*)alloc((size_t)768 * 512 * 2);
  unsigned short* Vtb = (unsigned short*)alloc((size_t)768 * 512 * 2);
  unsigned short* attnc = (unsigned short*)alloc((size_t)8192 * 512 * 2);
  int* cnt = (int*)alloc(12 * 4);
  int* idx = (int*)alloc((size_t)12 * 2048 * 4);
  int* offs = (int*)alloc(13 * 4);
  int* glob = (int*)alloc(8192 * 4);
  int* mcnt = (int*)alloc(4);
  int* mlist = (int*)alloc(8192 * 4);

  hipMemsetAsync(cnt, 0, 12 * 4, stream);
  hipMemsetAsync(mcnt, 0, 4, stream);
  hipMemsetAsync(glob, 0, 8192 * 4, stream);

  cvt_bf16<<<768, 256, 0, stream>>>(latent, latbf, (long)768 * 2048);

  dim3 tb(32, 8);
  transpose_split<<<dim3(16, 128), tb, 0, stream>>>(W_q, WqT_h, WqT_l, 4096, 512);
  transpose_split<<<dim3(32, 64), tb, 0, stream>>>(W_vk, WvkT_h, WvkT_l, 2048, 1024);
  transpose_split<<<dim3(128, 16), tb, 0, stream>>>(W_out, WoT_h, WoT_l, 512, 4096);

  gather_rows<<<32, 256, 0, stream>>>(mask, cnt, idx, mcnt, mlist);
  scan_offsets<<<1, 64, 0, stream>>>(cnt, offs);
  build_glob<<<12, 256, 0, stream>>>(cnt, offs, idx, glob);
  zerofill<<<2048, 256, 0, stream>>>(mcnt, mlist, out);

  // compact y -> bf16 (valid rows only)
  cvt_gather<<<16384, 256, 0, stream>>>(y, glob, offs, ybf);

  // kv = latent[768,2048] @ W_vk ; epilogue -> Kh/Kl, Vt
  gemm2<2, 1, true><<<(768 / BM) * (1024 / BN), 256, 0, stream>>>(
      latbf, WvkT_h, WvkT_l, Khb, Klb, Vtb, nullptr, nullptr, 768, 1024, 2048);
  // q = ybf[compact,4096] @ W_q -> fp32 split-K partials (2 slices), stride QCAP
  gemm2<1, 2, true><<<(8192 / BM) * (512 / BN) * 2, 256, 0, stream>>>(
      ybf, WqT_h, WqT_l, qc, nullptr, nullptr, nullptr, offs, QCAP, 512, 4096);
  // MFMA attention on compact positions
  attn5<<<12 * 64, 256, 0, stream>>>(qc, qc + (size_t)QCAP * 512, Khb, Klb,
                                     Vtb, cnt, offs, attnc);
  // out = attnc[compact,512] @ W_out (single-bf16 B) -> scatter fp32 rows
  gemm2<3, 1, false><<<(8192 / BM) * (4096 / BN), 256, 0, stream>>>(
      attnc, WoT_h, nullptr, out, nullptr, nullptr, glob, offs, 8192, 4096, 512);
}

// Round 10
// 344.531 us; speedup vs baseline: 1.1043x; 1.0510x over previous
//
#include <hip/hip_runtime.h>
#include <hip/hip_bf16.h>

typedef __attribute__((ext_vector_type(4))) float f32x4;
typedef __attribute__((ext_vector_type(8))) short bf16x8;
typedef __attribute__((ext_vector_type(8))) unsigned short u16x8;

#define QCAP 8256  // compact q buffer row capacity

__device__ __forceinline__ unsigned short f2bf(float f) {
  unsigned int u = __builtin_bit_cast(unsigned int, f);
  unsigned int r = (u + 0x7FFFu + ((u >> 16) & 1u)) >> 16;
  return (unsigned short)r;
}
__device__ __forceinline__ float bf2f(unsigned short h) {
  unsigned int u = ((unsigned int)h) << 16;
  return __builtin_bit_cast(float, u);
}

__device__ __forceinline__ void gload_lds16(const void* g, void* l) {
  __builtin_amdgcn_global_load_lds(
      (__attribute__((address_space(1))) unsigned int*)g,
      (__attribute__((address_space(3))) unsigned int*)l, 16, 0, 0);
}

// ---------- fp32 -> bf16 bulk convert (dense; used for latent) ----------
__global__ __launch_bounds__(256) void cvt_bf16(const float* __restrict__ in,
                                                unsigned short* __restrict__ out,
                                                long n) {
  long i = ((long)blockIdx.x * 256 + threadIdx.x) * 8;
  if (i >= n) return;
  f32x4 a = *(const f32x4*)(in + i);
  f32x4 b = *(const f32x4*)(in + i + 4);
  u16x8 o;
#pragma unroll
  for (int j = 0; j < 4; ++j) o[j] = f2bf(a[j]);
#pragma unroll
  for (int j = 0; j < 4; ++j) o[4 + j] = f2bf(b[j]);
  *(u16x8*)(out + i) = o;
}

// ---------- gathered fp32 -> bf16 convert for y (compact valid rows) ----------
__global__ __launch_bounds__(256) void cvt_gather(
    const float* __restrict__ y, const int* __restrict__ glob,
    const int* __restrict__ offs, unsigned short* __restrict__ ybf) {
  int p = blockIdx.x >> 1, half = blockIdx.x & 1;
  if (p >= offs[12]) return;
  int g = glob[p];
  const float* src = y + (size_t)g * 4096 + half * 2048 + threadIdx.x * 8;
  unsigned short* dst = ybf + (size_t)p * 4096 + half * 2048 + threadIdx.x * 8;
  f32x4 a = *(const f32x4*)src;
  f32x4 b = *(const f32x4*)(src + 4);
  u16x8 o;
#pragma unroll
  for (int j = 0; j < 4; ++j) o[j] = f2bf(a[j]);
#pragma unroll
  for (int j = 0; j < 4; ++j) o[4 + j] = f2bf(b[j]);
  *(u16x8*)dst = o;
}

// ---------- fused weight transpose + hi/lo split (all 3 weights, 1 launch) ----------
// ranges: [0,2048) W_q 4096x512; [2048,4096) W_vk 2048x1024; [4096,6144) W_out 512x4096
__global__ __launch_bounds__(256) void transpose_split3(
    const float* __restrict__ Wq, const float* __restrict__ Wvk,
    const float* __restrict__ Wo, unsigned short* __restrict__ QTh,
    unsigned short* __restrict__ QTl, unsigned short* __restrict__ VKh,
    unsigned short* __restrict__ VKl, unsigned short* __restrict__ OTh,
    unsigned short* __restrict__ OTl) {
  __shared__ float tile[32][33];
  int bid = blockIdx.x;
  const float* W;
  unsigned short *Th, *Tl;
  int K, N, nbx, b;
  if (bid < 2048) {
    W = Wq; Th = QTh; Tl = QTl; K = 4096; N = 512; nbx = 16; b = bid;
  } else if (bid < 4096) {
    W = Wvk; Th = VKh; Tl = VKl; K = 2048; N = 1024; nbx = 32; b = bid - 2048;
  } else {
    W = Wo; Th = OTh; Tl = OTl; K = 512; N = 4096; nbx = 128; b = bid - 4096;
  }
  int n0 = (b % nbx) * 32, k0 = (b / nbx) * 32;
  int tx = threadIdx.x & 31, ty = threadIdx.x >> 5;  // (32, 8)
#pragma unroll
  for (int r = 0; r < 4; ++r)
    tile[ty + 8 * r][tx] = W[(size_t)(k0 + ty + 8 * r) * N + n0 + tx];
  __syncthreads();
#pragma unroll
  for (int r = 0; r < 4; ++r) {
    float f = tile[tx][ty + 8 * r];
    unsigned short hi = f2bf(f);
    unsigned short lo = f2bf(f - bf2f(hi));
    size_t o = (size_t)(n0 + ty + 8 * r) * K + k0 + tx;
    Th[o] = hi;
    Tl[o] = lo;
  }
}

// ---------- gather rows by (b, t); also collect masked rows ----------
__global__ __launch_bounds__(256) void gather_rows(const int* __restrict__ mask,
                                                   int* __restrict__ cnt,
                                                   int* __restrict__ idx,
                                                   int* __restrict__ mcnt,
                                                   int* __restrict__ mlist) {
  int g = blockIdx.x * 256 + threadIdx.x;  // 0..8191
  int m = mask[g];
  if (m > 0) {
    int bt = (g >> 11) * 3 + m - 1;
    int p = atomicAdd(&cnt[bt], 1);
    idx[bt * 2048 + p] = g;
  } else {
    int p = atomicAdd(mcnt, 1);
    mlist[p] = g;
  }
}

// ---------- exclusive scan of 12 bucket counts ----------
__global__ void scan_offsets(const int* __restrict__ cnt, int* __restrict__ offs) {
  if (threadIdx.x == 0) {
    int s = 0;
#pragma unroll
    for (int i = 0; i < 12; ++i) {
      offs[i] = s;
      s += cnt[i];
    }
    offs[12] = s;
  }
}

// ---------- build bucket-major global compact list ----------
__global__ __launch_bounds__(256) void build_glob(const int* __restrict__ cnt,
                                                  const int* __restrict__ offs,
                                                  const int* __restrict__ idx,
                                                  int* __restrict__ glob) {
  int bt = blockIdx.x;
  int n = cnt[bt], o = offs[bt];
  for (int j = threadIdx.x; j < n; j += 256) glob[o + j] = idx[bt * 2048 + j];
}

// ---------- zero-fill out rows for masked queries ----------
__global__ __launch_bounds__(256) void zerofill(const int* __restrict__ mcnt,
                                                const int* __restrict__ mlist,
                                                float* __restrict__ out) {
  int w = blockIdx.x * 4 + (threadIdx.x >> 6);
  int lane = threadIdx.x & 63;
  if (w >= *mcnt) return;
  float* row = out + (size_t)mlist[w] * 4096;
  f32x4 z = (f32x4){0.f, 0.f, 0.f, 0.f};
#pragma unroll
  for (int i = 0; i < 16; ++i) *(f32x4*)(row + i * 256 + lane * 4) = z;
}

// ---------- bf16x2 / bf16 GEMM, swizzled LDS, LDS-reshape epilogue ----------
// EPI 1: fp32 split-K partial (contiguous rows), EPI 2: kv scatter epilogue,
// EPI 3: fp32 row-scatter via glob. EPI 1/3 route acc through LDS so stores
// are 512 B contiguous per output row (write-coalescing fix).
#define BM 128
#define BN 128
#define BK 64

template <int EPI, int KSL, bool USE_BL>
__global__ __launch_bounds__(256) void gemm2(
    const unsigned short* __restrict__ A, const unsigned short* __restrict__ Bh,
    const unsigned short* __restrict__ Bl, void* __restrict__ Cv,
    void* __restrict__ Cv2, void* __restrict__ Cv3,
    const int* __restrict__ glob, const int* __restrict__ offs, int M, int N,
    int K) {
  __shared__ unsigned short smem[BM * BK + BN * BK + (USE_BL ? BN * BK : 64)];
  unsigned short* Ald = smem;
  unsigned short* Bhld = smem + BM * BK;
  unsigned short* Blld = smem + BM * BK + BN * BK;
  float* epi = (float*)smem;  // 32 KB reuse after K-loop

  int tid = threadIdx.x, lane = tid & 63, wid = tid >> 6;
  int wr = wid >> 1, wc = wid & 1;
  int nwg = gridDim.x;
  int w = (blockIdx.x & 7) * (nwg >> 3) + (blockIdx.x >> 3);  // XCD swizzle
  int nTN = N / BN;
  int bm, bn, ks;
  if constexpr (KSL == 1) {
    bm = w / nTN;
    bn = w % nTN;
    ks = 0;
  } else {
    bm = w / (nTN * KSL);
    int r = w % (nTN * KSL);
    bn = r / KSL;
    ks = r % KSL;
  }
  int mv = M;
  if constexpr (EPI == 1 || EPI == 3) mv = offs[12];
  if (bm * BM >= mv) return;  // block-uniform early exit

  int kbeg = ks * (K / KSL), kend = kbeg + K / KSL;
  const unsigned short* Ab = A + (size_t)(bm * BM) * K;
  const unsigned short* Bhb = Bh + (size_t)(bn * BN) * K;
  const unsigned short* Blb = USE_BL ? Bl + (size_t)(bn * BN) * K : nullptr;
  int fr = lane & 15, fq = lane >> 4;
  int srow = lane >> 3, scol = ((lane & 7) ^ (lane >> 3)) * 8;  // pre-swizzled

  f32x4 acc[4][4];
#pragma unroll
  for (int i = 0; i < 4; ++i)
#pragma unroll
    for (int j = 0; j < 4; ++j) acc[i][j] = (f32x4){0.f, 0.f, 0.f, 0.f};

  for (int k0 = kbeg; k0 < kend; k0 += BK) {
#pragma unroll
    for (int i = 0; i < 4; ++i) {
      int c = wid * 4 + i;
      size_t go = (size_t)(c * 8 + srow) * K + k0 + scol;
      gload_lds16(Ab + go, &Ald[c * 512]);
      gload_lds16(Bhb + go, &Bhld[c * 512]);
      if constexpr (USE_BL) gload_lds16(Blb + go, &Blld[c * 512]);
    }
    __syncthreads();
#pragma unroll
    for (int kk = 0; kk < 2; ++kk) {
      int ca = (kk * 32 + fq * 8) ^ ((fr & 7) * 8);  // swizzled read col
      bf16x8 af[4], bhf[4], blf[4];
#pragma unroll
      for (int i = 0; i < 4; ++i) {
        af[i] = *(const bf16x8*)&Ald[(wr * 64 + i * 16 + fr) * BK + ca];
        bhf[i] = *(const bf16x8*)&Bhld[(wc * 64 + i * 16 + fr) * BK + ca];
        if constexpr (USE_BL)
          blf[i] = *(const bf16x8*)&Blld[(wc * 64 + i * 16 + fr) * BK + ca];
      }
#pragma unroll
      for (int mi = 0; mi < 4; ++mi)
#pragma unroll
        for (int ni = 0; ni < 4; ++ni) {
          acc[mi][ni] = __builtin_amdgcn_mfma_f32_16x16x32_bf16(
              af[mi], bhf[ni], acc[mi][ni], 0, 0, 0);
          if constexpr (USE_BL)
            acc[mi][ni] = __builtin_amdgcn_mfma_f32_16x16x32_bf16(
                af[mi], blf[ni], acc[mi][ni], 0, 0, 0);
        }
    }
    __syncthreads();
  }

  if constexpr (EPI == 2) {  // kv epilogue: direct scatter (tiny output)
#pragma unroll
    for (int mi = 0; mi < 4; ++mi)
#pragma unroll
      for (int ni = 0; ni < 4; ++ni)
#pragma unroll
        for (int r = 0; r < 4; ++r) {
          int row = bm * BM + wr * 64 + mi * 16 + fq * 4 + r;
          int col = bn * BN + wc * 64 + ni * 16 + fr;
          int bt = row >> 6, key = row & 63;
          float v = acc[mi][ni][r];
          if (col < 512) {
            int h = col >> 6, d = col & 63;
            unsigned short hi = f2bf(v);
            unsigned short lo = f2bf(v - bf2f(hi));
            size_t o = ((size_t)(bt * 8 + h) * 64 + key) * 64 + d;
            ((unsigned short*)Cv)[o] = hi;   // Kh
            ((unsigned short*)Cv2)[o] = lo;  // Kl
          } else {
            int c = col - 512;
            int h = c >> 6, d = c & 63;
            ((unsigned short*)Cv3)[((size_t)(bt * 8 + h) * 64 + d) * 64 + key] =
                f2bf(v);  // Vt
          }
        }
  } else {
    // LDS-reshape epilogue: 2 passes of 64 rows; 512B-contiguous row stores.
#pragma unroll 1
    for (int p = 0; p < 2; ++p) {
      __syncthreads();
      if (wr == p) {
#pragma unroll
        for (int mi = 0; mi < 4; ++mi)
#pragma unroll
          for (int ni = 0; ni < 4; ++ni)
#pragma unroll
            for (int r = 0; r < 4; ++r) {
              int lrow = mi * 16 + fq * 4 + r;           // 0..63
              int lcol = wc * 64 + ni * 16 + fr;         // 0..127
              int pc = lcol ^ ((lrow & 7) << 4);         // bank swizzle
              epi[lrow * 128 + pc] = acc[mi][ni][r];
            }
      }
      __syncthreads();
#pragma unroll
      for (int k = 0; k < 8; ++k) {
        int chunk = k * 256 + tid;       // 0..2047
        int lrow = chunk >> 5;           // 0..63
        int c4 = (chunk & 31) * 4;       // fp32 col, 16B-aligned
        int pc4 = c4 ^ ((lrow & 7) << 4);
        f32x4 v = *(f32x4*)&epi[lrow * 128 + pc4];
        int row = bm * BM + p * 64 + lrow;
        if constexpr (EPI == 1) {
          *(f32x4*)&((float*)Cv)[(size_t)ks * M * N + (size_t)row * N +
                                 bn * BN + c4] = v;
        } else {  // EPI == 3
          if (row < mv)
            *(f32x4*)&((float*)Cv)[(size_t)glob[row] * N + bn * BN + c4] = v;
        }
      }
    }
  }
}

// ---------- MFMA attention (compact positions) ----------
__global__ __launch_bounds__(256) void attn5(
    const float* __restrict__ q0, const float* __restrict__ q1,
    const unsigned short* __restrict__ Kh, const unsigned short* __restrict__ Kl,
    const unsigned short* __restrict__ Vt, const int* __restrict__ cnt,
    const int* __restrict__ offs, unsigned short* __restrict__ attnc) {
  __shared__ unsigned short Pl[4][32][72];
  int tid = threadIdx.x, wid = tid >> 6, lane = tid & 63;
  int fr = lane & 15, fq = lane >> 4;
  int bt = blockIdx.x >> 6, rt = blockIdx.x & 63;
  int n = cnt[bt];
  int rbase = rt * 32;
  if (rbase >= n) return;
  int qbase = offs[bt] + rbase;

#pragma unroll 1
  for (int hp = 0; hp < 2; ++hp) {
    int h = wid * 2 + hp;
    const unsigned short* khb = Kh + ((size_t)(bt * 8 + h) * 64) * 64;
    const unsigned short* klb = Kl + ((size_t)(bt * 8 + h) * 64) * 64;
    const unsigned short* vtb = Vt + ((size_t)(bt * 8 + h) * 64) * 64;

    f32x4 sacc[2][4];
#pragma unroll
    for (int i = 0; i < 2; ++i)
#pragma unroll
      for (int j = 0; j < 4; ++j) sacc[i][j] = (f32x4){0.f, 0.f, 0.f, 0.f};

#pragma unroll
    for (int kk = 0; kk < 2; ++kk) {
      bf16x8 qh[2], ql[2];
#pragma unroll
      for (int mi = 0; mi < 2; ++mi) {
        size_t qo = (size_t)(qbase + mi * 16 + fr) * 512 + h * 64 + kk * 32 + fq * 8;
        f32x4 a0 = *(const f32x4*)(q0 + qo);
        f32x4 a1 = *(const f32x4*)(q0 + qo + 4);
        f32x4 b0 = *(const f32x4*)(q1 + qo);
        f32x4 b1 = *(const f32x4*)(q1 + qo + 4);
        float sv[8];
        *(f32x4*)&sv[0] = a0 + b0;
        *(f32x4*)&sv[4] = a1 + b1;
#pragma unroll
        for (int j = 0; j < 8; ++j) {
          unsigned short hi = f2bf(sv[j]);
          qh[mi][j] = (short)hi;
          ql[mi][j] = (short)f2bf(sv[j] - bf2f(hi));
        }
      }
#pragma unroll
      for (int ni = 0; ni < 4; ++ni) {
        size_t ko = (size_t)(ni * 16 + fr) * 64 + kk * 32 + fq * 8;
        bf16x8 kh = *(const bf16x8*)(khb + ko);
        bf16x8 kl = *(const bf16x8*)(klb + ko);
#pragma unroll
        for (int mi = 0; mi < 2; ++mi) {
          sacc[mi][ni] = __builtin_amdgcn_mfma_f32_16x16x32_bf16(
              qh[mi], kh, sacc[mi][ni], 0, 0, 0);
          sacc[mi][ni] = __builtin_amdgcn_mfma_f32_16x16x32_bf16(
              qh[mi], kl, sacc[mi][ni], 0, 0, 0);
          sacc[mi][ni] = __builtin_amdgcn_mfma_f32_16x16x32_bf16(
              ql[mi], kh, sacc[mi][ni], 0, 0, 0);
        }
      }
    }

#pragma unroll
    for (int mi = 0; mi < 2; ++mi) {
#pragma unroll
      for (int r = 0; r < 4; ++r) {
        float m = fmaxf(fmaxf(sacc[mi][0][r], sacc[mi][1][r]),
                        fmaxf(sacc[mi][2][r], sacc[mi][3][r]));
#pragma unroll
        for (int o = 1; o < 16; o <<= 1) m = fmaxf(m, __shfl_xor(m, o));
        float e0 = __expf(sacc[mi][0][r] - m);
        float e1 = __expf(sacc[mi][1][r] - m);
        float e2 = __expf(sacc[mi][2][r] - m);
        float e3 = __expf(sacc[mi][3][r] - m);
        float s = e0 + e1 + e2 + e3;
#pragma unroll
        for (int o = 1; o < 16; o <<= 1) s += __shfl_xor(s, o);
        float inv = 1.f / s;
        int row = mi * 16 + fq * 4 + r;
        Pl[wid][row][fr] = f2bf(e0 * inv);
        Pl[wid][row][16 + fr] = f2bf(e1 * inv);
        Pl[wid][row][32 + fr] = f2bf(e2 * inv);
        Pl[wid][row][48 + fr] = f2bf(e3 * inv);
      }
    }

    f32x4 oacc[2][4];
#pragma unroll
    for (int i = 0; i < 2; ++i)
#pragma unroll
      for (int j = 0; j < 4; ++j) oacc[i][j] = (f32x4){0.f, 0.f, 0.f, 0.f};
#pragma unroll
    for (int kk = 0; kk < 2; ++kk) {
      bf16x8 pa[2];
#pragma unroll
      for (int mi = 0; mi < 2; ++mi)
        pa[mi] = *(const bf16x8*)&Pl[wid][mi * 16 + fr][kk * 32 + fq * 8];
#pragma unroll
      for (int ni = 0; ni < 4; ++ni) {
        bf16x8 vb = *(const bf16x8*)(vtb + (size_t)(ni * 16 + fr) * 64 +
                                     kk * 32 + fq * 8);
#pragma unroll
        for (int mi = 0; mi < 2; ++mi)
          oacc[mi][ni] = __builtin_amdgcn_mfma_f32_16x16x32_bf16(
              pa[mi], vb, oacc[mi][ni], 0, 0, 0);
      }
    }

#pragma unroll
    for (int mi = 0; mi < 2; ++mi)
#pragma unroll
      for (int r = 0; r < 4; ++r) {
        int row = mi * 16 + fq * 4 + r;
        if (rbase + row < n) {
          unsigned short* ar = attnc + (size_t)(qbase + row) * 512 + h * 64 + fr;
          ar[0] = f2bf(oacc[mi][0][r]);
          ar[16] = f2bf(oacc[mi][1][r]);
          ar[32] = f2bf(oacc[mi][2][r]);
          ar[48] = f2bf(oacc[mi][3][r]);
        }
      }
  }
}

// ---------- launch ----------
extern "C" void kernel_launch(void* const* d_in, const int* in_sizes, int n_in,
                              void* d_out, int out_size, void* d_ws,
                              size_t ws_size, hipStream_t stream) {
  const float* latent = (const float*)d_in[0];
  const float* y = (const float*)d_in[1];
  const int* mask = (const int*)d_in[2];
  const float* W_vk = (const float*)d_in[3];
  const float* W_q = (const float*)d_in[4];
  const float* W_out = (const float*)d_in[5];
  float* out = (float*)d_out;

  char* ws = (char*)d_ws;
  size_t off = 0;
  auto alloc = [&](size_t bytes) -> void* {
    void* p = ws + off;
    off = (off + bytes + 255) & ~(size_t)255;
    return p;
  };
  unsigned short* WqT_h = (unsigned short*)alloc((size_t)512 * 4096 * 2);
  unsigned short* WqT_l = (unsigned short*)alloc((size_t)512 * 4096 * 2);
  unsigned short* WvkT_h = (unsigned short*)alloc((size_t)1024 * 2048 * 2);
  unsigned short* WvkT_l = (unsigned short*)alloc((size_t)1024 * 2048 * 2);
  unsigned short* WoT_h = (unsigned short*)alloc((size_t)4096 * 512 * 2);
  unsigned short* WoT_l = (unsigned short*)alloc((size_t)4096 * 512 * 2);
  unsigned short* ybf = (unsigned short*)alloc((size_t)8192 * 4096 * 2);
  unsigned short* latbf = (unsigned short*)alloc((size_t)768 * 2048 * 2);
  float* qc = (float*)alloc((size_t)2 * QCAP * 512 * 4);
  unsigned short* Khb = (unsigned short*)alloc((size_t)768 * 512 * 2);
  unsigned short* Klb = (unsigned short*)alloc((size_t)768 * 512 * 2);
  unsigned short* Vtb = (unsigned short*)alloc((size_t)768 * 512 * 2);
  unsigned short* attnc = (unsigned short*)alloc((size_t)8192 * 512 * 2);
  int* cnt = (int*)alloc(12 * 4);
  int* idx = (int*)alloc((size_t)12 * 2048 * 4);
  int* offs = (int*)alloc(13 * 4);
  int* glob = (int*)alloc(8192 * 4);
  int* mcnt = (int*)alloc(4);
  int* mlist = (int*)alloc(8192 * 4);

  hipMemsetAsync(cnt, 0, 12 * 4, stream);
  hipMemsetAsync(mcnt, 0, 4, stream);
  hipMemsetAsync(glob, 0, 8192 * 4, stream);

  cvt_bf16<<<768, 256, 0, stream>>>(latent, latbf, (long)768 * 2048);

  transpose_split3<<<6144, 256, 0, stream>>>(W_q, W_vk, W_out, WqT_h, WqT_l,
                                             WvkT_h, WvkT_l, WoT_h, WoT_l);

  gather_rows<<<32, 256, 0, stream>>>(mask, cnt, idx, mcnt, mlist);
  scan_offsets<<<1, 64, 0, stream>>>(cnt, offs);
  build_glob<<<12, 256, 0, stream>>>(cnt, offs, idx, glob);
  zerofill<<<2048, 256, 0, stream>>>(mcnt, mlist, out);

  cvt_gather<<<16384, 256, 0, stream>>>(y, glob, offs, ybf);

  // kv = latent[768,2048] @ W_vk ; epilogue -> Kh/Kl, Vt
  gemm2<2, 1, true><<<(768 / BM) * (1024 / BN), 256, 0, stream>>>(
      latbf, WvkT_h, WvkT_l, Khb, Klb, Vtb, nullptr, nullptr, 768, 1024, 2048);
  // q = ybf[compact,4096] @ W_q -> fp32 split-K partials, stride QCAP
  gemm2<1, 2, true><<<(8192 / BM) * (512 / BN) * 2, 256, 0, stream>>>(
      ybf, WqT_h, WqT_l, qc, nullptr, nullptr, nullptr, offs, QCAP, 512, 4096);
  // MFMA attention on compact positions
  attn5<<<12 * 64, 256, 0, stream>>>(qc, qc + (size_t)QCAP * 512, Khb, Klb,
                                     Vtb, cnt, offs, attnc);
  // out = attnc[compact,512] @ W_out (single-bf16 B) -> scatter fp32 rows
  gemm2<3, 1, false><<<(8192 / BM) * (4096 / BN), 256, 0, stream>>>(
      attnc, WoT_h, nullptr, out, nullptr, nullptr, glob, offs, 8192, 4096, 512);
}

// Round 11
// 321.892 us; speedup vs baseline: 1.1820x; 1.0703x over previous
//
#include <hip/hip_runtime.h>
#include <hip/hip_bf16.h>

typedef __attribute__((ext_vector_type(4))) float f32x4;
typedef __attribute__((ext_vector_type(8))) short bf16x8;
typedef __attribute__((ext_vector_type(4))) unsigned short u16x4;
typedef __attribute__((ext_vector_type(8))) unsigned short u16x8;

#define QCAP 8256  // compact q buffer row capacity
#define QSTR ((size_t)QCAP * 512)

__device__ __forceinline__ unsigned short f2bf(float f) {
  unsigned int u = __builtin_bit_cast(unsigned int, f);
  unsigned int r = (u + 0x7FFFu + ((u >> 16) & 1u)) >> 16;
  return (unsigned short)r;
}
__device__ __forceinline__ float bf2f(unsigned short h) {
  unsigned int u = ((unsigned int)h) << 16;
  return __builtin_bit_cast(float, u);
}

__device__ __forceinline__ void gload_lds16(const void* g, void* l) {
  __builtin_amdgcn_global_load_lds(
      (__attribute__((address_space(1))) unsigned int*)g,
      (__attribute__((address_space(3))) unsigned int*)l, 16, 0, 0);
}

// ---------- fp32 -> bf16 bulk convert (latent) ----------
__global__ __launch_bounds__(256) void cvt_bf16(const float* __restrict__ in,
                                                unsigned short* __restrict__ out,
                                                long n) {
  long i = ((long)blockIdx.x * 256 + threadIdx.x) * 8;
  if (i >= n) return;
  f32x4 a = *(const f32x4*)(in + i);
  f32x4 b = *(const f32x4*)(in + i + 4);
  u16x8 o;
#pragma unroll
  for (int j = 0; j < 4; ++j) o[j] = f2bf(a[j]);
#pragma unroll
  for (int j = 0; j < 4; ++j) o[4 + j] = f2bf(b[j]);
  *(u16x8*)(out + i) = o;
}

// ---------- gathered fp32 -> bf16 convert for y (compact valid rows) ----------
__global__ __launch_bounds__(256) void cvt_gather(
    const float* __restrict__ y, const int* __restrict__ glob,
    const int* __restrict__ offs, unsigned short* __restrict__ ybf) {
  int p = blockIdx.x >> 1, half = blockIdx.x & 1;
  if (p >= offs[12]) return;
  int g = glob[p];
  const float* src = y + (size_t)g * 4096 + half * 2048 + threadIdx.x * 8;
  unsigned short* dst = ybf + (size_t)p * 4096 + half * 2048 + threadIdx.x * 8;
  f32x4 a = *(const f32x4*)src;
  f32x4 b = *(const f32x4*)(src + 4);
  u16x8 o;
#pragma unroll
  for (int j = 0; j < 4; ++j) o[j] = f2bf(a[j]);
#pragma unroll
  for (int j = 0; j < 4; ++j) o[4 + j] = f2bf(b[j]);
  *(u16x8*)dst = o;
}

// ---------- fused weight transpose + hi/lo split ----------
__global__ __launch_bounds__(256) void transpose_split3(
    const float* __restrict__ Wq, const float* __restrict__ Wvk,
    const float* __restrict__ Wo, unsigned short* __restrict__ QTh,
    unsigned short* __restrict__ QTl, unsigned short* __restrict__ VKh,
    unsigned short* __restrict__ VKl, unsigned short* __restrict__ OTh,
    unsigned short* __restrict__ OTl) {
  __shared__ float tile[32][33];
  int bid = blockIdx.x;
  const float* W;
  unsigned short *Th, *Tl;
  int K, N, nbx, b;
  if (bid < 2048) {
    W = Wq; Th = QTh; Tl = QTl; K = 4096; N = 512; nbx = 16; b = bid;
  } else if (bid < 4096) {
    W = Wvk; Th = VKh; Tl = VKl; K = 2048; N = 1024; nbx = 32; b = bid - 2048;
  } else {
    W = Wo; Th = OTh; Tl = OTl; K = 512; N = 4096; nbx = 128; b = bid - 4096;
  }
  int n0 = (b % nbx) * 32, k0 = (b / nbx) * 32;
  int tx = threadIdx.x & 31, ty = threadIdx.x >> 5;
#pragma unroll
  for (int r = 0; r < 4; ++r)
    tile[ty + 8 * r][tx] = W[(size_t)(k0 + ty + 8 * r) * N + n0 + tx];
  __syncthreads();
#pragma unroll
  for (int r = 0; r < 4; ++r) {
    float f = tile[tx][ty + 8 * r];
    unsigned short hi = f2bf(f);
    unsigned short lo = f2bf(f - bf2f(hi));
    size_t o = (size_t)(n0 + ty + 8 * r) * K + k0 + tx;
    Th[o] = hi;
    Tl[o] = lo;
  }
}

// ---------- gather rows by (b, t); also collect masked rows ----------
__global__ __launch_bounds__(256) void gather_rows(const int* __restrict__ mask,
                                                   int* __restrict__ cnt,
                                                   int* __restrict__ idx,
                                                   int* __restrict__ mcnt,
                                                   int* __restrict__ mlist) {
  int g = blockIdx.x * 256 + threadIdx.x;
  int m = mask[g];
  if (m > 0) {
    int bt = (g >> 11) * 3 + m - 1;
    int p = atomicAdd(&cnt[bt], 1);
    idx[bt * 2048 + p] = g;
  } else {
    int p = atomicAdd(mcnt, 1);
    mlist[p] = g;
  }
}

// ---------- scan (local) + build bucket-major compact list ----------
__global__ __launch_bounds__(256) void scan_build(const int* __restrict__ cnt,
                                                  int* __restrict__ offs,
                                                  const int* __restrict__ idx,
                                                  int* __restrict__ glob) {
  __shared__ int so[13];
  if (threadIdx.x == 0) {
    int s = 0;
#pragma unroll
    for (int i = 0; i < 12; ++i) {
      so[i] = s;
      s += cnt[i];
    }
    so[12] = s;
    if (blockIdx.x == 0)
#pragma unroll
      for (int i = 0; i < 13; ++i) offs[i] = so[i];
  }
  __syncthreads();
  int bt = blockIdx.x;
  int n = cnt[bt], o = so[bt];
  for (int j = threadIdx.x; j < n; j += 256) glob[o + j] = idx[bt * 2048 + j];
}

// ---------- zero-fill out rows for masked queries ----------
__global__ __launch_bounds__(256) void zerofill(const int* __restrict__ mcnt,
                                                const int* __restrict__ mlist,
                                                float* __restrict__ out) {
  int w = blockIdx.x * 4 + (threadIdx.x >> 6);
  int lane = threadIdx.x & 63;
  if (w >= *mcnt) return;
  float* row = out + (size_t)mlist[w] * 4096;
  f32x4 z = (f32x4){0.f, 0.f, 0.f, 0.f};
#pragma unroll
  for (int i = 0; i < 16; ++i) *(f32x4*)(row + i * 256 + lane * 4) = z;
}

// ---------- kv finish: sum 4 split-K partials, hi/lo split + scatter ----------
// kvp: [4][768][1024] fp32 -> Kh/Kl [bt][h][key][d], Vt [bt][h][d][key]
__global__ __launch_bounds__(256) void kv_finish(const float* __restrict__ kvp,
                                                 unsigned short* __restrict__ Kh,
                                                 unsigned short* __restrict__ Kl,
                                                 unsigned short* __restrict__ Vt) {
  int row = blockIdx.x;  // 0..767
  int bt = row >> 6, key = row & 63;
  int c = threadIdx.x * 4;
  const float* p = kvp + (size_t)row * 1024 + c;
  f32x4 v = *(const f32x4*)p;
#pragma unroll
  for (int sl = 1; sl < 4; ++sl)
    v += *(const f32x4*)(p + (size_t)sl * 768 * 1024);
  if (c < 512) {
    int h = c >> 6, d = c & 63;
    u16x4 hv, lv;
#pragma unroll
    for (int j = 0; j < 4; ++j) {
      unsigned short hi = f2bf(v[j]);
      hv[j] = hi;
      lv[j] = f2bf(v[j] - bf2f(hi));
    }
    size_t o = ((size_t)(bt * 8 + h) * 64 + key) * 64 + d;
    *(u16x4*)&Kh[o] = hv;
    *(u16x4*)&Kl[o] = lv;
  } else {
    int cc = c - 512;
    int h = cc >> 6, d = cc & 63;
#pragma unroll
    for (int j = 0; j < 4; ++j)
      Vt[((size_t)(bt * 8 + h) * 64 + d + j) * 64 + key] = f2bf(v[j]);
  }
}

// ---------- bf16x2 / bf16 GEMM, swizzled LDS, LDS-reshape epilogue ----------
// EPI 1: fp32 split-K partial, compact (early-exit past offs[12])
// EPI 3: fp32 row-scatter via glob (compact)
// EPI 4: fp32 split-K partial, full M (kv)
#define BM 128
#define BN 128
#define BK 64

template <int EPI, int KSL, bool USE_BL>
__global__ __launch_bounds__(256) void gemm2(
    const unsigned short* __restrict__ A, const unsigned short* __restrict__ Bh,
    const unsigned short* __restrict__ Bl, void* __restrict__ Cv,
    const int* __restrict__ glob, const int* __restrict__ offs, int M, int N,
    int K) {
  __shared__ unsigned short smem[BM * BK + BN * BK + (USE_BL ? BN * BK : 64)];
  unsigned short* Ald = smem;
  unsigned short* Bhld = smem + BM * BK;
  unsigned short* Blld = smem + BM * BK + BN * BK;
  float* epi = (float*)smem;  // 32 KB reuse after K-loop

  int tid = threadIdx.x, lane = tid & 63, wid = tid >> 6;
  int wr = wid >> 1, wc = wid & 1;
  int nwg = gridDim.x;
  int w = (blockIdx.x & 7) * (nwg >> 3) + (blockIdx.x >> 3);  // XCD swizzle
  int nTN = N / BN;
  int bm, bn, ks;
  if constexpr (KSL == 1) {
    bm = w / nTN;
    bn = w % nTN;
    ks = 0;
  } else {
    bm = w / (nTN * KSL);
    int r = w % (nTN * KSL);
    bn = r / KSL;
    ks = r % KSL;
  }
  int mv = M;
  if constexpr (EPI == 1 || EPI == 3) mv = offs[12];
  if (bm * BM >= mv) return;

  int kbeg = ks * (K / KSL), kend = kbeg + K / KSL;
  const unsigned short* Ab = A + (size_t)(bm * BM) * K;
  const unsigned short* Bhb = Bh + (size_t)(bn * BN) * K;
  const unsigned short* Blb = USE_BL ? Bl + (size_t)(bn * BN) * K : nullptr;
  int fr = lane & 15, fq = lane >> 4;
  int srow = lane >> 3, scol = ((lane & 7) ^ (lane >> 3)) * 8;  // pre-swizzled

  f32x4 acc[4][4];
#pragma unroll
  for (int i = 0; i < 4; ++i)
#pragma unroll
    for (int j = 0; j < 4; ++j) acc[i][j] = (f32x4){0.f, 0.f, 0.f, 0.f};

  for (int k0 = kbeg; k0 < kend; k0 += BK) {
#pragma unroll
    for (int i = 0; i < 4; ++i) {
      int c = wid * 4 + i;
      size_t go = (size_t)(c * 8 + srow) * K + k0 + scol;
      gload_lds16(Ab + go, &Ald[c * 512]);
      gload_lds16(Bhb + go, &Bhld[c * 512]);
      if constexpr (USE_BL) gload_lds16(Blb + go, &Blld[c * 512]);
    }
    __syncthreads();
#pragma unroll
    for (int kk = 0; kk < 2; ++kk) {
      int ca = (kk * 32 + fq * 8) ^ ((fr & 7) * 8);  // swizzled read col
      bf16x8 af[4], bhf[4], blf[4];
#pragma unroll
      for (int i = 0; i < 4; ++i) {
        af[i] = *(const bf16x8*)&Ald[(wr * 64 + i * 16 + fr) * BK + ca];
        bhf[i] = *(const bf16x8*)&Bhld[(wc * 64 + i * 16 + fr) * BK + ca];
        if constexpr (USE_BL)
          blf[i] = *(const bf16x8*)&Blld[(wc * 64 + i * 16 + fr) * BK + ca];
      }
#pragma unroll
      for (int mi = 0; mi < 4; ++mi)
#pragma unroll
        for (int ni = 0; ni < 4; ++ni) {
          acc[mi][ni] = __builtin_amdgcn_mfma_f32_16x16x32_bf16(
              af[mi], bhf[ni], acc[mi][ni], 0, 0, 0);
          if constexpr (USE_BL)
            acc[mi][ni] = __builtin_amdgcn_mfma_f32_16x16x32_bf16(
                af[mi], blf[ni], acc[mi][ni], 0, 0, 0);
        }
    }
    __syncthreads();
  }

  // LDS-reshape epilogue: 2 passes of 64 rows; 512B-contiguous row stores.
#pragma unroll 1
  for (int p = 0; p < 2; ++p) {
    __syncthreads();
    if (wr == p) {
#pragma unroll
      for (int mi = 0; mi < 4; ++mi)
#pragma unroll
        for (int ni = 0; ni < 4; ++ni)
#pragma unroll
          for (int r = 0; r < 4; ++r) {
            int lrow = mi * 16 + fq * 4 + r;
            int lcol = wc * 64 + ni * 16 + fr;
            int pc = lcol ^ ((lrow & 7) << 4);
            epi[lrow * 128 + pc] = acc[mi][ni][r];
          }
    }
    __syncthreads();
#pragma unroll
    for (int k = 0; k < 8; ++k) {
      int chunk = k * 256 + tid;
      int lrow = chunk >> 5;
      int c4 = (chunk & 31) * 4;
      int pc4 = c4 ^ ((lrow & 7) << 4);
      f32x4 v = *(f32x4*)&epi[lrow * 128 + pc4];
      int row = bm * BM + p * 64 + lrow;
      if constexpr (EPI == 1 || EPI == 4) {
        *(f32x4*)&((float*)Cv)[(size_t)ks * M * N + (size_t)row * N + bn * BN +
                               c4] = v;
      } else {  // EPI == 3
        if (row < mv)
          *(f32x4*)&((float*)Cv)[(size_t)glob[row] * N + bn * BN + c4] = v;
      }
    }
  }
}

// ---------- MFMA attention (compact positions, sums 4 q partials) ----------
__global__ __launch_bounds__(256) void attn5(
    const float* __restrict__ qc, const unsigned short* __restrict__ Kh,
    const unsigned short* __restrict__ Kl, const unsigned short* __restrict__ Vt,
    const int* __restrict__ cnt, const int* __restrict__ offs,
    unsigned short* __restrict__ attnc) {
  __shared__ unsigned short Pl[4][32][72];
  int tid = threadIdx.x, wid = tid >> 6, lane = tid & 63;
  int fr = lane & 15, fq = lane >> 4;
  int bt = blockIdx.x >> 6, rt = blockIdx.x & 63;
  int n = cnt[bt];
  int rbase = rt * 32;
  if (rbase >= n) return;
  int qbase = offs[bt] + rbase;

#pragma unroll 1
  for (int hp = 0; hp < 2; ++hp) {
    int h = wid * 2 + hp;
    const unsigned short* khb = Kh + ((size_t)(bt * 8 + h) * 64) * 64;
    const unsigned short* klb = Kl + ((size_t)(bt * 8 + h) * 64) * 64;
    const unsigned short* vtb = Vt + ((size_t)(bt * 8 + h) * 64) * 64;

    f32x4 sacc[2][4];
#pragma unroll
    for (int i = 0; i < 2; ++i)
#pragma unroll
      for (int j = 0; j < 4; ++j) sacc[i][j] = (f32x4){0.f, 0.f, 0.f, 0.f};

#pragma unroll
    for (int kk = 0; kk < 2; ++kk) {
      bf16x8 qh[2], ql[2];
#pragma unroll
      for (int mi = 0; mi < 2; ++mi) {
        size_t qo = (size_t)(qbase + mi * 16 + fr) * 512 + h * 64 + kk * 32 + fq * 8;
        f32x4 s0 = *(const f32x4*)(qc + qo);
        f32x4 s1 = *(const f32x4*)(qc + qo + 4);
#pragma unroll
        for (int sl = 1; sl < 4; ++sl) {
          s0 += *(const f32x4*)(qc + sl * QSTR + qo);
          s1 += *(const f32x4*)(qc + sl * QSTR + qo + 4);
        }
        float sv[8];
        *(f32x4*)&sv[0] = s0;
        *(f32x4*)&sv[4] = s1;
#pragma unroll
        for (int j = 0; j < 8; ++j) {
          unsigned short hi = f2bf(sv[j]);
          qh[mi][j] = (short)hi;
          ql[mi][j] = (short)f2bf(sv[j] - bf2f(hi));
        }
      }
#pragma unroll
      for (int ni = 0; ni < 4; ++ni) {
        size_t ko = (size_t)(ni * 16 + fr) * 64 + kk * 32 + fq * 8;
        bf16x8 kh = *(const bf16x8*)(khb + ko);
        bf16x8 kl = *(const bf16x8*)(klb + ko);
#pragma unroll
        for (int mi = 0; mi < 2; ++mi) {
          sacc[mi][ni] = __builtin_amdgcn_mfma_f32_16x16x32_bf16(
              qh[mi], kh, sacc[mi][ni], 0, 0, 0);
          sacc[mi][ni] = __builtin_amdgcn_mfma_f32_16x16x32_bf16(
              qh[mi], kl, sacc[mi][ni], 0, 0, 0);
          sacc[mi][ni] = __builtin_amdgcn_mfma_f32_16x16x32_bf16(
              ql[mi], kh, sacc[mi][ni], 0, 0, 0);
        }
      }
    }

#pragma unroll
    for (int mi = 0; mi < 2; ++mi) {
#pragma unroll
      for (int r = 0; r < 4; ++r) {
        float m = fmaxf(fmaxf(sacc[mi][0][r], sacc[mi][1][r]),
                        fmaxf(sacc[mi][2][r], sacc[mi][3][r]));
#pragma unroll
        for (int o = 1; o < 16; o <<= 1) m = fmaxf(m, __shfl_xor(m, o));
        float e0 = __expf(sacc[mi][0][r] - m);
        float e1 = __expf(sacc[mi][1][r] - m);
        float e2 = __expf(sacc[mi][2][r] - m);
        float e3 = __expf(sacc[mi][3][r] - m);
        float s = e0 + e1 + e2 + e3;
#pragma unroll
        for (int o = 1; o < 16; o <<= 1) s += __shfl_xor(s, o);
        float inv = 1.f / s;
        int row = mi * 16 + fq * 4 + r;
        Pl[wid][row][fr] = f2bf(e0 * inv);
        Pl[wid][row][16 + fr] = f2bf(e1 * inv);
        Pl[wid][row][32 + fr] = f2bf(e2 * inv);
        Pl[wid][row][48 + fr] = f2bf(e3 * inv);
      }
    }

    f32x4 oacc[2][4];
#pragma unroll
    for (int i = 0; i < 2; ++i)
#pragma unroll
      for (int j = 0; j < 4; ++j) oacc[i][j] = (f32x4){0.f, 0.f, 0.f, 0.f};
#pragma unroll
    for (int kk = 0; kk < 2; ++kk) {
      bf16x8 pa[2];
#pragma unroll
      for (int mi = 0; mi < 2; ++mi)
        pa[mi] = *(const bf16x8*)&Pl[wid][mi * 16 + fr][kk * 32 + fq * 8];
#pragma unroll
      for (int ni = 0; ni < 4; ++ni) {
        bf16x8 vb = *(const bf16x8*)(vtb + (size_t)(ni * 16 + fr) * 64 +
                                     kk * 32 + fq * 8);
#pragma unroll
        for (int mi = 0; mi < 2; ++mi)
          oacc[mi][ni] = __builtin_amdgcn_mfma_f32_16x16x32_bf16(
              pa[mi], vb, oacc[mi][ni], 0, 0, 0);
      }
    }

#pragma unroll
    for (int mi = 0; mi < 2; ++mi)
#pragma unroll
      for (int r = 0; r < 4; ++r) {
        int row = mi * 16 + fq * 4 + r;
        if (rbase + row < n) {
          unsigned short* ar = attnc + (size_t)(qbase + row) * 512 + h * 64 + fr;
          ar[0] = f2bf(oacc[mi][0][r]);
          ar[16] = f2bf(oacc[mi][1][r]);
          ar[32] = f2bf(oacc[mi][2][r]);
          ar[48] = f2bf(oacc[mi][3][r]);
        }
      }
  }
}

// ---------- launch ----------
extern "C" void kernel_launch(void* const* d_in, const int* in_sizes, int n_in,
                              void* d_out, int out_size, void* d_ws,
                              size_t ws_size, hipStream_t stream) {
  const float* latent = (const float*)d_in[0];
  const float* y = (const float*)d_in[1];
  const int* mask = (const int*)d_in[2];
  const float* W_vk = (const float*)d_in[3];
  const float* W_q = (const float*)d_in[4];
  const float* W_out = (const float*)d_in[5];
  float* out = (float*)d_out;

  char* ws = (char*)d_ws;
  size_t off = 0;
  auto alloc = [&](size_t bytes) -> void* {
    void* p = ws + off;
    off = (off + bytes + 255) & ~(size_t)255;
    return p;
  };
  unsigned short* WqT_h = (unsigned short*)alloc((size_t)512 * 4096 * 2);
  unsigned short* WqT_l = (unsigned short*)alloc((size_t)512 * 4096 * 2);
  unsigned short* WvkT_h = (unsigned short*)alloc((size_t)1024 * 2048 * 2);
  unsigned short* WvkT_l = (unsigned short*)alloc((size_t)1024 * 2048 * 2);
  unsigned short* WoT_h = (unsigned short*)alloc((size_t)4096 * 512 * 2);
  unsigned short* WoT_l = (unsigned short*)alloc((size_t)4096 * 512 * 2);
  unsigned short* ybf = (unsigned short*)alloc((size_t)8192 * 4096 * 2);
  unsigned short* latbf = (unsigned short*)alloc((size_t)768 * 2048 * 2);
  float* qc = (float*)alloc((size_t)4 * QCAP * 512 * 4);  // 4 split-K slices
  float* kvp = qc;  // kv partials alias qc (dead before q-GEMM writes qc)
  unsigned short* Khb = (unsigned short*)alloc((size_t)768 * 512 * 2);
  unsigned short* Klb = (unsigned short*)alloc((size_t)768 * 512 * 2);
  unsigned short* Vtb = (unsigned short*)alloc((size_t)768 * 512 * 2);
  unsigned short* attnc = (unsigned short*)alloc((size_t)8192 * 512 * 2);
  int* cnt = (int*)alloc(12 * 4);
  int* idx = (int*)alloc((size_t)12 * 2048 * 4);
  int* offs = (int*)alloc(13 * 4);
  int* glob = (int*)alloc(8192 * 4);
  int* mcnt = (int*)alloc(4);
  int* mlist = (int*)alloc(8192 * 4);

  hipMemsetAsync(cnt, 0, 12 * 4, stream);
  hipMemsetAsync(mcnt, 0, 4, stream);
  hipMemsetAsync(glob, 0, 8192 * 4, stream);

  cvt_bf16<<<768, 256, 0, stream>>>(latent, latbf, (long)768 * 2048);

  transpose_split3<<<6144, 256, 0, stream>>>(W_q, W_vk, W_out, WqT_h, WqT_l,
                                             WvkT_h, WvkT_l, WoT_h, WoT_l);

  gather_rows<<<32, 256, 0, stream>>>(mask, cnt, idx, mcnt, mlist);
  scan_build<<<12, 256, 0, stream>>>(cnt, offs, idx, glob);
  zerofill<<<2048, 256, 0, stream>>>(mcnt, mlist, out);

  cvt_gather<<<16384, 256, 0, stream>>>(y, glob, offs, ybf);

  // kv = latent[768,2048] @ W_vk -> 4 fp32 partial slices (192 blocks)
  gemm2<4, 4, true><<<(768 / BM) * (1024 / BN) * 4, 256, 0, stream>>>(
      latbf, WvkT_h, WvkT_l, kvp, nullptr, nullptr, 768, 1024, 2048);
  kv_finish<<<768, 256, 0, stream>>>(kvp, Khb, Klb, Vtb);
  // q = ybf[compact,4096] @ W_q -> 4 fp32 split-K slices, stride QCAP
  gemm2<1, 4, true><<<(8192 / BM) * (512 / BN) * 4, 256, 0, stream>>>(
      ybf, WqT_h, WqT_l, qc, nullptr, offs, QCAP, 512, 4096);
  // MFMA attention (sums 4 q partials)
  attn5<<<12 * 64, 256, 0, stream>>>(qc, Khb, Klb, Vtb, cnt, offs, attnc);
  // out = attnc[compact,512] @ W_out (single-bf16 B) -> scatter fp32 rows
  gemm2<3, 1, false><<<(8192 / BM) * (4096 / BN), 256, 0, stream>>>(
      attnc, WoT_h, nullptr, out, glob, offs, 8192, 4096, 512);
}

// Round 12
// 313.049 us; speedup vs baseline: 1.2154x; 1.0282x over previous
//
#include <hip/hip_runtime.h>
#include <hip/hip_bf16.h>

typedef __attribute__((ext_vector_type(4))) float f32x4;
typedef __attribute__((ext_vector_type(8))) short bf16x8;
typedef __attribute__((ext_vector_type(4))) unsigned short u16x4;
typedef __attribute__((ext_vector_type(8))) unsigned short u16x8;

#define QCAP 8256  // compact q buffer row capacity
#define QSTR ((size_t)QCAP * 512)

__device__ __forceinline__ unsigned short f2bf(float f) {
  unsigned int u = __builtin_bit_cast(unsigned int, f);
  unsigned int r = (u + 0x7FFFu + ((u >> 16) & 1u)) >> 16;
  return (unsigned short)r;
}
__device__ __forceinline__ float bf2f(unsigned short h) {
  unsigned int u = ((unsigned int)h) << 16;
  return __builtin_bit_cast(float, u);
}

__device__ __forceinline__ void gload_lds16(const void* g, void* l) {
  __builtin_amdgcn_global_load_lds(
      (__attribute__((address_space(1))) unsigned int*)g,
      (__attribute__((address_space(3))) unsigned int*)l, 16, 0, 0);
}

// ---------- fp32 -> bf16 bulk convert (latent) ----------
__global__ __launch_bounds__(256) void cvt_bf16(const float* __restrict__ in,
                                                unsigned short* __restrict__ out,
                                                long n) {
  long i = ((long)blockIdx.x * 256 + threadIdx.x) * 8;
  if (i >= n) return;
  f32x4 a = *(const f32x4*)(in + i);
  f32x4 b = *(const f32x4*)(in + i + 4);
  u16x8 o;
#pragma unroll
  for (int j = 0; j < 4; ++j) o[j] = f2bf(a[j]);
#pragma unroll
  for (int j = 0; j < 4; ++j) o[4 + j] = f2bf(b[j]);
  *(u16x8*)(out + i) = o;
}

// ---------- gathered fp32 -> bf16 convert for y (compact valid rows) ----------
__global__ __launch_bounds__(256) void cvt_gather(
    const float* __restrict__ y, const int* __restrict__ glob,
    const int* __restrict__ offs, unsigned short* __restrict__ ybf) {
  int p = blockIdx.x >> 1, half = blockIdx.x & 1;
  if (p >= offs[12]) return;
  int g = glob[p];
  const float* src = y + (size_t)g * 4096 + half * 2048 + threadIdx.x * 8;
  unsigned short* dst = ybf + (size_t)p * 4096 + half * 2048 + threadIdx.x * 8;
  f32x4 a = *(const f32x4*)src;
  f32x4 b = *(const f32x4*)(src + 4);
  u16x8 o;
#pragma unroll
  for (int j = 0; j < 4; ++j) o[j] = f2bf(a[j]);
#pragma unroll
  for (int j = 0; j < 4; ++j) o[4 + j] = f2bf(b[j]);
  *(u16x8*)dst = o;
}

// ---------- fused weight transpose + hi/lo split ----------
__global__ __launch_bounds__(256) void transpose_split3(
    const float* __restrict__ Wq, const float* __restrict__ Wvk,
    const float* __restrict__ Wo, unsigned short* __restrict__ QTh,
    unsigned short* __restrict__ QTl, unsigned short* __restrict__ VKh,
    unsigned short* __restrict__ VKl, unsigned short* __restrict__ OTh,
    unsigned short* __restrict__ OTl) {
  __shared__ float tile[32][33];
  int bid = blockIdx.x;
  const float* W;
  unsigned short *Th, *Tl;
  int K, N, nbx, b;
  if (bid < 2048) {
    W = Wq; Th = QTh; Tl = QTl; K = 4096; N = 512; nbx = 16; b = bid;
  } else if (bid < 4096) {
    W = Wvk; Th = VKh; Tl = VKl; K = 2048; N = 1024; nbx = 32; b = bid - 2048;
  } else {
    W = Wo; Th = OTh; Tl = OTl; K = 512; N = 4096; nbx = 128; b = bid - 4096;
  }
  int n0 = (b % nbx) * 32, k0 = (b / nbx) * 32;
  int tx = threadIdx.x & 31, ty = threadIdx.x >> 5;
#pragma unroll
  for (int r = 0; r < 4; ++r)
    tile[ty + 8 * r][tx] = W[(size_t)(k0 + ty + 8 * r) * N + n0 + tx];
  __syncthreads();
#pragma unroll
  for (int r = 0; r < 4; ++r) {
    float f = tile[tx][ty + 8 * r];
    unsigned short hi = f2bf(f);
    unsigned short lo = f2bf(f - bf2f(hi));
    size_t o = (size_t)(n0 + ty + 8 * r) * K + k0 + tx;
    Th[o] = hi;
    Tl[o] = lo;
  }
}

// ---------- gather rows by (b, t); also collect masked rows ----------
__global__ __launch_bounds__(256) void gather_rows(const int* __restrict__ mask,
                                                   int* __restrict__ cnt,
                                                   int* __restrict__ idx,
                                                   int* __restrict__ mcnt,
                                                   int* __restrict__ mlist) {
  int g = blockIdx.x * 256 + threadIdx.x;
  int m = mask[g];
  if (m > 0) {
    int bt = (g >> 11) * 3 + m - 1;
    int p = atomicAdd(&cnt[bt], 1);
    idx[bt * 2048 + p] = g;
  } else {
    int p = atomicAdd(mcnt, 1);
    mlist[p] = g;
  }
}

// ---------- scan (local) + build bucket-major compact list ----------
__global__ __launch_bounds__(256) void scan_build(const int* __restrict__ cnt,
                                                  int* __restrict__ offs,
                                                  const int* __restrict__ idx,
                                                  int* __restrict__ glob) {
  __shared__ int so[13];
  if (threadIdx.x == 0) {
    int s = 0;
#pragma unroll
    for (int i = 0; i < 12; ++i) {
      so[i] = s;
      s += cnt[i];
    }
    so[12] = s;
    if (blockIdx.x == 0)
#pragma unroll
      for (int i = 0; i < 13; ++i) offs[i] = so[i];
  }
  __syncthreads();
  int bt = blockIdx.x;
  int n = cnt[bt], o = so[bt];
  for (int j = threadIdx.x; j < n; j += 256) glob[o + j] = idx[bt * 2048 + j];
}

// ---------- zero-fill out rows for masked queries ----------
__global__ __launch_bounds__(256) void zerofill(const int* __restrict__ mcnt,
                                                const int* __restrict__ mlist,
                                                float* __restrict__ out) {
  int w = blockIdx.x * 4 + (threadIdx.x >> 6);
  int lane = threadIdx.x & 63;
  if (w >= *mcnt) return;
  float* row = out + (size_t)mlist[w] * 4096;
  f32x4 z = (f32x4){0.f, 0.f, 0.f, 0.f};
#pragma unroll
  for (int i = 0; i < 16; ++i) *(f32x4*)(row + i * 256 + lane * 4) = z;
}

// ---------- kv finish: sum 4 split-K partials, hi/lo split + scatter ----------
__global__ __launch_bounds__(256) void kv_finish(const float* __restrict__ kvp,
                                                 unsigned short* __restrict__ Kh,
                                                 unsigned short* __restrict__ Kl,
                                                 unsigned short* __restrict__ Vt) {
  int row = blockIdx.x;  // 0..767
  int bt = row >> 6, key = row & 63;
  int c = threadIdx.x * 4;
  const float* p = kvp + (size_t)row * 1024 + c;
  f32x4 v = *(const f32x4*)p;
#pragma unroll
  for (int sl = 1; sl < 4; ++sl)
    v += *(const f32x4*)(p + (size_t)sl * 768 * 1024);
  if (c < 512) {
    int h = c >> 6, d = c & 63;
    u16x4 hv, lv;
#pragma unroll
    for (int j = 0; j < 4; ++j) {
      unsigned short hi = f2bf(v[j]);
      hv[j] = hi;
      lv[j] = f2bf(v[j] - bf2f(hi));
    }
    size_t o = ((size_t)(bt * 8 + h) * 64 + key) * 64 + d;
    *(u16x4*)&Kh[o] = hv;
    *(u16x4*)&Kl[o] = lv;
  } else {
    int cc = c - 512;
    int h = cc >> 6, d = cc & 63;
#pragma unroll
    for (int j = 0; j < 4; ++j)
      Vt[((size_t)(bt * 8 + h) * 64 + d + j) * 64 + key] = f2bf(v[j]);
  }
}

// ---------- bf16x2 / bf16 GEMM, swizzled LDS, LDS-reshape epilogue ----------
// EPI 1: fp32 split-K partial, compact M (bm fastest-varying so dead tiles
//        spread uniformly across XCDs after the swizzle)
// EPI 3: fp32 row-scatter via glob, compact M (bm fastest-varying)
// EPI 4: fp32 split-K partial, full M (kv; bm-major kept)
#define BM 128
#define BN 128
#define BK 64

template <int EPI, int KSL, bool USE_BL>
__global__ __launch_bounds__(256) void gemm2(
    const unsigned short* __restrict__ A, const unsigned short* __restrict__ Bh,
    const unsigned short* __restrict__ Bl, void* __restrict__ Cv,
    const int* __restrict__ glob, const int* __restrict__ offs, int M, int N,
    int K) {
  __shared__ unsigned short smem[BM * BK + BN * BK + (USE_BL ? BN * BK : 64)];
  unsigned short* Ald = smem;
  unsigned short* Bhld = smem + BM * BK;
  unsigned short* Blld = smem + BM * BK + BN * BK;
  float* epi = (float*)smem;  // 32 KB reuse after K-loop

  int tid = threadIdx.x, lane = tid & 63, wid = tid >> 6;
  int wr = wid >> 1, wc = wid & 1;
  int nwg = gridDim.x;
  int w = (blockIdx.x & 7) * (nwg >> 3) + (blockIdx.x >> 3);  // XCD swizzle
  int nTN = N / BN;
  int bm, bn, ks;
  if constexpr (EPI == 1 || EPI == 3) {
    // bm fastest: dead (compacted-away) tiles interleave across XCD chunks;
    // each chunk keeps one (bn,ks) weight panel L2-resident.
    int nBM = M / BM;
    bm = w % nBM;
    int r = w / nBM;
    if constexpr (KSL == 1) {
      bn = r;
      ks = 0;
    } else {
      bn = r / KSL;
      ks = r % KSL;
    }
  } else {
    if constexpr (KSL == 1) {
      bm = w / nTN;
      bn = w % nTN;
      ks = 0;
    } else {
      bm = w / (nTN * KSL);
      int r = w % (nTN * KSL);
      bn = r / KSL;
      ks = r % KSL;
    }
  }
  int mv = M;
  if constexpr (EPI == 1 || EPI == 3) mv = offs[12];
  if (bm * BM >= mv) return;

  int kbeg = ks * (K / KSL), kend = kbeg + K / KSL;
  const unsigned short* Ab = A + (size_t)(bm * BM) * K;
  const unsigned short* Bhb = Bh + (size_t)(bn * BN) * K;
  const unsigned short* Blb = USE_BL ? Bl + (size_t)(bn * BN) * K : nullptr;
  int fr = lane & 15, fq = lane >> 4;
  int srow = lane >> 3, scol = ((lane & 7) ^ (lane >> 3)) * 8;  // pre-swizzled

  f32x4 acc[4][4];
#pragma unroll
  for (int i = 0; i < 4; ++i)
#pragma unroll
    for (int j = 0; j < 4; ++j) acc[i][j] = (f32x4){0.f, 0.f, 0.f, 0.f};

  for (int k0 = kbeg; k0 < kend; k0 += BK) {
#pragma unroll
    for (int i = 0; i < 4; ++i) {
      int c = wid * 4 + i;
      size_t go = (size_t)(c * 8 + srow) * K + k0 + scol;
      gload_lds16(Ab + go, &Ald[c * 512]);
      gload_lds16(Bhb + go, &Bhld[c * 512]);
      if constexpr (USE_BL) gload_lds16(Blb + go, &Blld[c * 512]);
    }
    __syncthreads();
#pragma unroll
    for (int kk = 0; kk < 2; ++kk) {
      int ca = (kk * 32 + fq * 8) ^ ((fr & 7) * 8);  // swizzled read col
      bf16x8 af[4], bhf[4], blf[4];
#pragma unroll
      for (int i = 0; i < 4; ++i) {
        af[i] = *(const bf16x8*)&Ald[(wr * 64 + i * 16 + fr) * BK + ca];
        bhf[i] = *(const bf16x8*)&Bhld[(wc * 64 + i * 16 + fr) * BK + ca];
        if constexpr (USE_BL)
          blf[i] = *(const bf16x8*)&Blld[(wc * 64 + i * 16 + fr) * BK + ca];
      }
#pragma unroll
      for (int mi = 0; mi < 4; ++mi)
#pragma unroll
        for (int ni = 0; ni < 4; ++ni) {
          acc[mi][ni] = __builtin_amdgcn_mfma_f32_16x16x32_bf16(
              af[mi], bhf[ni], acc[mi][ni], 0, 0, 0);
          if constexpr (USE_BL)
            acc[mi][ni] = __builtin_amdgcn_mfma_f32_16x16x32_bf16(
                af[mi], blf[ni], acc[mi][ni], 0, 0, 0);
        }
    }
    __syncthreads();
  }

  // LDS-reshape epilogue: 2 passes of 64 rows; 512B-contiguous row stores.
#pragma unroll 1
  for (int p = 0; p < 2; ++p) {
    __syncthreads();
    if (wr == p) {
#pragma unroll
      for (int mi = 0; mi < 4; ++mi)
#pragma unroll
        for (int ni = 0; ni < 4; ++ni)
#pragma unroll
          for (int r = 0; r < 4; ++r) {
            int lrow = mi * 16 + fq * 4 + r;
            int lcol = wc * 64 + ni * 16 + fr;
            int pc = lcol ^ ((lrow & 7) << 4);
            epi[lrow * 128 + pc] = acc[mi][ni][r];
          }
    }
    __syncthreads();
#pragma unroll
    for (int k = 0; k < 8; ++k) {
      int chunk = k * 256 + tid;
      int lrow = chunk >> 5;
      int c4 = (chunk & 31) * 4;
      int pc4 = c4 ^ ((lrow & 7) << 4);
      f32x4 v = *(f32x4*)&epi[lrow * 128 + pc4];
      int row = bm * BM + p * 64 + lrow;
      if constexpr (EPI == 1 || EPI == 4) {
        *(f32x4*)&((float*)Cv)[(size_t)ks * M * N + (size_t)row * N + bn * BN +
                               c4] = v;
      } else {  // EPI == 3
        if (row < mv)
          *(f32x4*)&((float*)Cv)[(size_t)glob[row] * N + bn * BN + c4] = v;
      }
    }
  }
}

// ---------- MFMA attention (compact positions, sums 4 q partials) ----------
__global__ __launch_bounds__(256) void attn5(
    const float* __restrict__ qc, const unsigned short* __restrict__ Kh,
    const unsigned short* __restrict__ Kl, const unsigned short* __restrict__ Vt,
    const int* __restrict__ cnt, const int* __restrict__ offs,
    unsigned short* __restrict__ attnc) {
  __shared__ unsigned short Pl[4][32][72];
  int tid = threadIdx.x, wid = tid >> 6, lane = tid & 63;
  int fr = lane & 15, fq = lane >> 4;
  int bt = blockIdx.x >> 6, rt = blockIdx.x & 63;
  int n = cnt[bt];
  int rbase = rt * 32;
  if (rbase >= n) return;
  int qbase = offs[bt] + rbase;

#pragma unroll 1
  for (int hp = 0; hp < 2; ++hp) {
    int h = wid * 2 + hp;
    const unsigned short* khb = Kh + ((size_t)(bt * 8 + h) * 64) * 64;
    const unsigned short* klb = Kl + ((size_t)(bt * 8 + h) * 64) * 64;
    const unsigned short* vtb = Vt + ((size_t)(bt * 8 + h) * 64) * 64;

    f32x4 sacc[2][4];
#pragma unroll
    for (int i = 0; i < 2; ++i)
#pragma unroll
      for (int j = 0; j < 4; ++j) sacc[i][j] = (f32x4){0.f, 0.f, 0.f, 0.f};

#pragma unroll
    for (int kk = 0; kk < 2; ++kk) {
      bf16x8 qh[2], ql[2];
#pragma unroll
      for (int mi = 0; mi < 2; ++mi) {
        size_t qo = (size_t)(qbase + mi * 16 + fr) * 512 + h * 64 + kk * 32 + fq * 8;
        f32x4 s0 = *(const f32x4*)(qc + qo);
        f32x4 s1 = *(const f32x4*)(qc + qo + 4);
#pragma unroll
        for (int sl = 1; sl < 4; ++sl) {
          s0 += *(const f32x4*)(qc + sl * QSTR + qo);
          s1 += *(const f32x4*)(qc + sl * QSTR + qo + 4);
        }
        float sv[8];
        *(f32x4*)&sv[0] = s0;
        *(f32x4*)&sv[4] = s1;
#pragma unroll
        for (int j = 0; j < 8; ++j) {
          unsigned short hi = f2bf(sv[j]);
          qh[mi][j] = (short)hi;
          ql[mi][j] = (short)f2bf(sv[j] - bf2f(hi));
        }
      }
#pragma unroll
      for (int ni = 0; ni < 4; ++ni) {
        size_t ko = (size_t)(ni * 16 + fr) * 64 + kk * 32 + fq * 8;
        bf16x8 kh = *(const bf16x8*)(khb + ko);
        bf16x8 kl = *(const bf16x8*)(klb + ko);
#pragma unroll
        for (int mi = 0; mi < 2; ++mi) {
          sacc[mi][ni] = __builtin_amdgcn_mfma_f32_16x16x32_bf16(
              qh[mi], kh, sacc[mi][ni], 0, 0, 0);
          sacc[mi][ni] = __builtin_amdgcn_mfma_f32_16x16x32_bf16(
              qh[mi], kl, sacc[mi][ni], 0, 0, 0);
          sacc[mi][ni] = __builtin_amdgcn_mfma_f32_16x16x32_bf16(
              ql[mi], kh, sacc[mi][ni], 0, 0, 0);
        }
      }
    }

#pragma unroll
    for (int mi = 0; mi < 2; ++mi) {
#pragma unroll
      for (int r = 0; r < 4; ++r) {
        float m = fmaxf(fmaxf(sacc[mi][0][r], sacc[mi][1][r]),
                        fmaxf(sacc[mi][2][r], sacc[mi][3][r]));
#pragma unroll
        for (int o = 1; o < 16; o <<= 1) m = fmaxf(m, __shfl_xor(m, o));
        float e0 = __expf(sacc[mi][0][r] - m);
        float e1 = __expf(sacc[mi][1][r] - m);
        float e2 = __expf(sacc[mi][2][r] - m);
        float e3 = __expf(sacc[mi][3][r] - m);
        float s = e0 + e1 + e2 + e3;
#pragma unroll
        for (int o = 1; o < 16; o <<= 1) s += __shfl_xor(s, o);
        float inv = 1.f / s;
        int row = mi * 16 + fq * 4 + r;
        Pl[wid][row][fr] = f2bf(e0 * inv);
        Pl[wid][row][16 + fr] = f2bf(e1 * inv);
        Pl[wid][row][32 + fr] = f2bf(e2 * inv);
        Pl[wid][row][48 + fr] = f2bf(e3 * inv);
      }
    }

    f32x4 oacc[2][4];
#pragma unroll
    for (int i = 0; i < 2; ++i)
#pragma unroll
      for (int j = 0; j < 4; ++j) oacc[i][j] = (f32x4){0.f, 0.f, 0.f, 0.f};
#pragma unroll
    for (int kk = 0; kk < 2; ++kk) {
      bf16x8 pa[2];
#pragma unroll
      for (int mi = 0; mi < 2; ++mi)
        pa[mi] = *(const bf16x8*)&Pl[wid][mi * 16 + fr][kk * 32 + fq * 8];
#pragma unroll
      for (int ni = 0; ni < 4; ++ni) {
        bf16x8 vb = *(const bf16x8*)(vtb + (size_t)(ni * 16 + fr) * 64 +
                                     kk * 32 + fq * 8);
#pragma unroll
        for (int mi = 0; mi < 2; ++mi)
          oacc[mi][ni] = __builtin_amdgcn_mfma_f32_16x16x32_bf16(
              pa[mi], vb, oacc[mi][ni], 0, 0, 0);
      }
    }

#pragma unroll
    for (int mi = 0; mi < 2; ++mi)
#pragma unroll
      for (int r = 0; r < 4; ++r) {
        int row = mi * 16 + fq * 4 + r;
        if (rbase + row < n) {
          unsigned short* ar = attnc + (size_t)(qbase + row) * 512 + h * 64 + fr;
          ar[0] = f2bf(oacc[mi][0][r]);
          ar[16] = f2bf(oacc[mi][1][r]);
          ar[32] = f2bf(oacc[mi][2][r]);
          ar[48] = f2bf(oacc[mi][3][r]);
        }
      }
  }
}

// ---------- launch ----------
extern "C" void kernel_launch(void* const* d_in, const int* in_sizes, int n_in,
                              void* d_out, int out_size, void* d_ws,
                              size_t ws_size, hipStream_t stream) {
  const float* latent = (const float*)d_in[0];
  const float* y = (const float*)d_in[1];
  const int* mask = (const int*)d_in[2];
  const float* W_vk = (const float*)d_in[3];
  const float* W_q = (const float*)d_in[4];
  const float* W_out = (const float*)d_in[5];
  float* out = (float*)d_out;

  char* ws = (char*)d_ws;
  size_t off = 0;
  auto alloc = [&](size_t bytes) -> void* {
    void* p = ws + off;
    off = (off + bytes + 255) & ~(size_t)255;
    return p;
  };
  unsigned short* WqT_h = (unsigned short*)alloc((size_t)512 * 4096 * 2);
  unsigned short* WqT_l = (unsigned short*)alloc((size_t)512 * 4096 * 2);
  unsigned short* WvkT_h = (unsigned short*)alloc((size_t)1024 * 2048 * 2);
  unsigned short* WvkT_l = (unsigned short*)alloc((size_t)1024 * 2048 * 2);
  unsigned short* WoT_h = (unsigned short*)alloc((size_t)4096 * 512 * 2);
  unsigned short* WoT_l = (unsigned short*)alloc((size_t)4096 * 512 * 2);
  unsigned short* ybf = (unsigned short*)alloc((size_t)8192 * 4096 * 2);
  unsigned short* latbf = (unsigned short*)alloc((size_t)768 * 2048 * 2);
  float* qc = (float*)alloc((size_t)4 * QCAP * 512 * 4);  // 4 split-K slices
  float* kvp = qc;  // kv partials alias qc (dead before q-GEMM writes qc)
  unsigned short* Khb = (unsigned short*)alloc((size_t)768 * 512 * 2);
  unsigned short* Klb = (unsigned short*)alloc((size_t)768 * 512 * 2);
  unsigned short* Vtb = (unsigned short*)alloc((size_t)768 * 512 * 2);
  unsigned short* attnc = (unsigned short*)alloc((size_t)8192 * 512 * 2);
  int* cnt = (int*)alloc(12 * 4);
  int* idx = (int*)alloc((size_t)12 * 2048 * 4);
  int* offs = (int*)alloc(13 * 4);
  int* glob = (int*)alloc(8192 * 4);
  int* mcnt = (int*)alloc(4);
  int* mlist = (int*)alloc(8192 * 4);

  hipMemsetAsync(cnt, 0, 12 * 4, stream);
  hipMemsetAsync(mcnt, 0, 4, stream);
  hipMemsetAsync(glob, 0, 8192 * 4, stream);

  cvt_bf16<<<768, 256, 0, stream>>>(latent, latbf, (long)768 * 2048);

  transpose_split3<<<6144, 256, 0, stream>>>(W_q, W_vk, W_out, WqT_h, WqT_l,
                                             WvkT_h, WvkT_l, WoT_h, WoT_l);

  gather_rows<<<32, 256, 0, stream>>>(mask, cnt, idx, mcnt, mlist);
  scan_build<<<12, 256, 0, stream>>>(cnt, offs, idx, glob);
  zerofill<<<2048, 256, 0, stream>>>(mcnt, mlist, out);

  cvt_gather<<<16384, 256, 0, stream>>>(y, glob, offs, ybf);

  // kv = latent[768,2048] @ W_vk -> 4 fp32 partial slices
  gemm2<4, 4, true><<<(768 / BM) * (1024 / BN) * 4, 256, 0, stream>>>(
      latbf, WvkT_h, WvkT_l, kvp, nullptr, nullptr, 768, 1024, 2048);
  kv_finish<<<768, 256, 0, stream>>>(kvp, Khb, Klb, Vtb);
  // q = ybf[compact,4096] @ W_q -> 4 fp32 split-K slices, stride QCAP
  gemm2<1, 4, true><<<(8192 / BM) * (512 / BN) * 4, 256, 0, stream>>>(
      ybf, WqT_h, WqT_l, qc, nullptr, offs, QCAP, 512, 4096);
  // MFMA attention (sums 4 q partials)
  attn5<<<12 * 64, 256, 0, stream>>>(qc, Khb, Klb, Vtb, cnt, offs, attnc);
  // out = attnc[compact,512] @ W_out (single-bf16 B) -> scatter fp32 rows
  gemm2<3, 1, false><<<(8192 / BM) * (4096 / BN), 256, 0, stream>>>(
      attnc, WoT_h, nullptr, out, glob, offs, 8192, 4096, 512);
}

// Round 13
// 295.831 us; speedup vs baseline: 1.2861x; 1.0582x over previous
//
#include <hip/hip_runtime.h>
#include <hip/hip_bf16.h>

typedef __attribute__((ext_vector_type(4))) float f32x4;
typedef __attribute__((ext_vector_type(8))) short bf16x8;
typedef __attribute__((ext_vector_type(4))) unsigned short u16x4;
typedef __attribute__((ext_vector_type(8))) unsigned short u16x8;

#define QCAP 8256  // compact q buffer row capacity
#define QSTR ((size_t)QCAP * 512)

__device__ __forceinline__ unsigned short f2bf(float f) {
  unsigned int u = __builtin_bit_cast(unsigned int, f);
  unsigned int r = (u + 0x7FFFu + ((u >> 16) & 1u)) >> 16;
  return (unsigned short)r;
}
__device__ __forceinline__ float bf2f(unsigned short h) {
  unsigned int u = ((unsigned int)h) << 16;
  return __builtin_bit_cast(float, u);
}

__device__ __forceinline__ void gload_lds16(const void* g, void* l) {
  __builtin_amdgcn_global_load_lds(
      (__attribute__((address_space(1))) unsigned int*)g,
      (__attribute__((address_space(3))) unsigned int*)l, 16, 0, 0);
}

// ---------- fp32 -> bf16 bulk convert (latent) ----------
__global__ __launch_bounds__(256) void cvt_bf16(const float* __restrict__ in,
                                                unsigned short* __restrict__ out,
                                                long n) {
  long i = ((long)blockIdx.x * 256 + threadIdx.x) * 8;
  if (i >= n) return;
  f32x4 a = *(const f32x4*)(in + i);
  f32x4 b = *(const f32x4*)(in + i + 4);
  u16x8 o;
#pragma unroll
  for (int j = 0; j < 4; ++j) o[j] = f2bf(a[j]);
#pragma unroll
  for (int j = 0; j < 4; ++j) o[4 + j] = f2bf(b[j]);
  *(u16x8*)(out + i) = o;
}

// ---------- gathered fp32 -> bf16 convert for y (compact valid rows) ----------
__global__ __launch_bounds__(256) void cvt_gather(
    const float* __restrict__ y, const int* __restrict__ glob,
    const int* __restrict__ offs, unsigned short* __restrict__ ybf) {
  int p = blockIdx.x >> 1, half = blockIdx.x & 1;
  if (p >= offs[12]) return;
  int g = glob[p];
  const float* src = y + (size_t)g * 4096 + half * 2048 + threadIdx.x * 8;
  unsigned short* dst = ybf + (size_t)p * 4096 + half * 2048 + threadIdx.x * 8;
  f32x4 a = *(const f32x4*)src;
  f32x4 b = *(const f32x4*)(src + 4);
  u16x8 o;
#pragma unroll
  for (int j = 0; j < 4; ++j) o[j] = f2bf(a[j]);
#pragma unroll
  for (int j = 0; j < 4; ++j) o[4 + j] = f2bf(b[j]);
  *(u16x8*)dst = o;
}

// ---------- fused weight transpose + hi/lo split ----------
__global__ __launch_bounds__(256) void transpose_split3(
    const float* __restrict__ Wq, const float* __restrict__ Wvk,
    const float* __restrict__ Wo, unsigned short* __restrict__ QTh,
    unsigned short* __restrict__ QTl, unsigned short* __restrict__ VKh,
    unsigned short* __restrict__ VKl, unsigned short* __restrict__ OTh,
    unsigned short* __restrict__ OTl) {
  __shared__ float tile[32][33];
  int bid = blockIdx.x;
  const float* W;
  unsigned short *Th, *Tl;
  int K, N, nbx, b;
  if (bid < 2048) {
    W = Wq; Th = QTh; Tl = QTl; K = 4096; N = 512; nbx = 16; b = bid;
  } else if (bid < 4096) {
    W = Wvk; Th = VKh; Tl = VKl; K = 2048; N = 1024; nbx = 32; b = bid - 2048;
  } else {
    W = Wo; Th = OTh; Tl = OTl; K = 512; N = 4096; nbx = 128; b = bid - 4096;
  }
  int n0 = (b % nbx) * 32, k0 = (b / nbx) * 32;
  int tx = threadIdx.x & 31, ty = threadIdx.x >> 5;
#pragma unroll
  for (int r = 0; r < 4; ++r)
    tile[ty + 8 * r][tx] = W[(size_t)(k0 + ty + 8 * r) * N + n0 + tx];
  __syncthreads();
#pragma unroll
  for (int r = 0; r < 4; ++r) {
    float f = tile[tx][ty + 8 * r];
    unsigned short hi = f2bf(f);
    unsigned short lo = f2bf(f - bf2f(hi));
    size_t o = (size_t)(n0 + ty + 8 * r) * K + k0 + tx;
    Th[o] = hi;
    Tl[o] = lo;
  }
}

// ---------- gather rows by (b, t); also collect masked rows ----------
__global__ __launch_bounds__(256) void gather_rows(const int* __restrict__ mask,
                                                   int* __restrict__ cnt,
                                                   int* __restrict__ idx,
                                                   int* __restrict__ mcnt,
                                                   int* __restrict__ mlist) {
  int g = blockIdx.x * 256 + threadIdx.x;
  int m = mask[g];
  if (m > 0) {
    int bt = (g >> 11) * 3 + m - 1;
    int p = atomicAdd(&cnt[bt], 1);
    idx[bt * 2048 + p] = g;
  } else {
    int p = atomicAdd(mcnt, 1);
    mlist[p] = g;
  }
}

// ---------- scan (local) + build bucket-major compact list ----------
__global__ __launch_bounds__(256) void scan_build(const int* __restrict__ cnt,
                                                  int* __restrict__ offs,
                                                  const int* __restrict__ idx,
                                                  int* __restrict__ glob) {
  __shared__ int so[13];
  if (threadIdx.x == 0) {
    int s = 0;
#pragma unroll
    for (int i = 0; i < 12; ++i) {
      so[i] = s;
      s += cnt[i];
    }
    so[12] = s;
    if (blockIdx.x == 0)
#pragma unroll
      for (int i = 0; i < 13; ++i) offs[i] = so[i];
  }
  __syncthreads();
  int bt = blockIdx.x;
  int n = cnt[bt], o = so[bt];
  for (int j = threadIdx.x; j < n; j += 256) glob[o + j] = idx[bt * 2048 + j];
}

// ---------- zero-fill out rows for masked queries ----------
__global__ __launch_bounds__(256) void zerofill(const int* __restrict__ mcnt,
                                                const int* __restrict__ mlist,
                                                float* __restrict__ out) {
  int w = blockIdx.x * 4 + (threadIdx.x >> 6);
  int lane = threadIdx.x & 63;
  if (w >= *mcnt) return;
  float* row = out + (size_t)mlist[w] * 4096;
  f32x4 z = (f32x4){0.f, 0.f, 0.f, 0.f};
#pragma unroll
  for (int i = 0; i < 16; ++i) *(f32x4*)(row + i * 256 + lane * 4) = z;
}

// ---------- kv finish: sum 4 split-K partials, hi/lo split + scatter ----------
__global__ __launch_bounds__(256) void kv_finish(const float* __restrict__ kvp,
                                                 unsigned short* __restrict__ Kh,
                                                 unsigned short* __restrict__ Kl,
                                                 unsigned short* __restrict__ Vt) {
  int row = blockIdx.x;  // 0..767
  int bt = row >> 6, key = row & 63;
  int c = threadIdx.x * 4;
  const float* p = kvp + (size_t)row * 1024 + c;
  f32x4 v = *(const f32x4*)p;
#pragma unroll
  for (int sl = 1; sl < 4; ++sl)
    v += *(const f32x4*)(p + (size_t)sl * 768 * 1024);
  if (c < 512) {
    int h = c >> 6, d = c & 63;
    u16x4 hv, lv;
#pragma unroll
    for (int j = 0; j < 4; ++j) {
      unsigned short hi = f2bf(v[j]);
      hv[j] = hi;
      lv[j] = f2bf(v[j] - bf2f(hi));
    }
    size_t o = ((size_t)(bt * 8 + h) * 64 + key) * 64 + d;
    *(u16x4*)&Kh[o] = hv;
    *(u16x4*)&Kl[o] = lv;
  } else {
    int cc = c - 512;
    int h = cc >> 6, d = cc & 63;
#pragma unroll
    for (int j = 0; j < 4; ++j)
      Vt[((size_t)(bt * 8 + h) * 64 + d + j) * 64 + key] = f2bf(v[j]);
  }
}

// ---------- bf16x2 / bf16 GEMM, swizzled LDS, LDS-reshape epilogue ----------
// EPI 1: fp32 split-K partial, compact M (bm fastest-varying)
// EPI 3: fp32 row-scatter via glob, compact M (bm fastest-varying)
// EPI 4: fp32 split-K partial, full M (kv; bm-major kept)
#define BM 128
#define BN 128
#define BK 64

template <int EPI, int KSL, bool USE_BL>
__global__ __launch_bounds__(256) void gemm2(
    const unsigned short* __restrict__ A, const unsigned short* __restrict__ Bh,
    const unsigned short* __restrict__ Bl, void* __restrict__ Cv,
    const int* __restrict__ glob, const int* __restrict__ offs, int M, int N,
    int K) {
  __shared__ unsigned short smem[BM * BK + BN * BK + (USE_BL ? BN * BK : 64)];
  unsigned short* Ald = smem;
  unsigned short* Bhld = smem + BM * BK;
  unsigned short* Blld = smem + BM * BK + BN * BK;
  float* epi = (float*)smem;  // 32 KB reuse after K-loop

  int tid = threadIdx.x, lane = tid & 63, wid = tid >> 6;
  int wr = wid >> 1, wc = wid & 1;
  int nwg = gridDim.x;
  int w = (blockIdx.x & 7) * (nwg >> 3) + (blockIdx.x >> 3);  // XCD swizzle
  int nTN = N / BN;
  int bm, bn, ks;
  if constexpr (EPI == 1 || EPI == 3) {
    // bm fastest: dead (compacted-away) tiles interleave across XCD chunks
    int nBM = M / BM;
    bm = w % nBM;
    int r = w / nBM;
    if constexpr (KSL == 1) {
      bn = r;
      ks = 0;
    } else {
      bn = r / KSL;
      ks = r % KSL;
    }
  } else {
    if constexpr (KSL == 1) {
      bm = w / nTN;
      bn = w % nTN;
      ks = 0;
    } else {
      bm = w / (nTN * KSL);
      int r = w % (nTN * KSL);
      bn = r / KSL;
      ks = r % KSL;
    }
  }
  int mv = M;
  if constexpr (EPI == 1 || EPI == 3) mv = offs[12];
  if (bm * BM >= mv) return;

  int kbeg = ks * (K / KSL), kend = kbeg + K / KSL;
  const unsigned short* Ab = A + (size_t)(bm * BM) * K;
  const unsigned short* Bhb = Bh + (size_t)(bn * BN) * K;
  const unsigned short* Blb = USE_BL ? Bl + (size_t)(bn * BN) * K : nullptr;
  int fr = lane & 15, fq = lane >> 4;
  int srow = lane >> 3, scol = ((lane & 7) ^ (lane >> 3)) * 8;  // pre-swizzled

  f32x4 acc[4][4];
#pragma unroll
  for (int i = 0; i < 4; ++i)
#pragma unroll
    for (int j = 0; j < 4; ++j) acc[i][j] = (f32x4){0.f, 0.f, 0.f, 0.f};

  for (int k0 = kbeg; k0 < kend; k0 += BK) {
#pragma unroll
    for (int i = 0; i < 4; ++i) {
      int c = wid * 4 + i;
      size_t go = (size_t)(c * 8 + srow) * K + k0 + scol;
      gload_lds16(Ab + go, &Ald[c * 512]);
      gload_lds16(Bhb + go, &Bhld[c * 512]);
      if constexpr (USE_BL) gload_lds16(Blb + go, &Blld[c * 512]);
    }
    __syncthreads();
#pragma unroll
    for (int kk = 0; kk < 2; ++kk) {
      int ca = (kk * 32 + fq * 8) ^ ((fr & 7) * 8);  // swizzled read col
      bf16x8 af[4], bhf[4], blf[4];
#pragma unroll
      for (int i = 0; i < 4; ++i) {
        af[i] = *(const bf16x8*)&Ald[(wr * 64 + i * 16 + fr) * BK + ca];
        bhf[i] = *(const bf16x8*)&Bhld[(wc * 64 + i * 16 + fr) * BK + ca];
        if constexpr (USE_BL)
          blf[i] = *(const bf16x8*)&Blld[(wc * 64 + i * 16 + fr) * BK + ca];
      }
#pragma unroll
      for (int mi = 0; mi < 4; ++mi)
#pragma unroll
        for (int ni = 0; ni < 4; ++ni) {
          acc[mi][ni] = __builtin_amdgcn_mfma_f32_16x16x32_bf16(
              af[mi], bhf[ni], acc[mi][ni], 0, 0, 0);
          if constexpr (USE_BL)
            acc[mi][ni] = __builtin_amdgcn_mfma_f32_16x16x32_bf16(
                af[mi], blf[ni], acc[mi][ni], 0, 0, 0);
        }
    }
    __syncthreads();
  }

  // LDS-reshape epilogue: 2 passes of 64 rows; 512B-contiguous row stores.
#pragma unroll 1
  for (int p = 0; p < 2; ++p) {
    __syncthreads();
    if (wr == p) {
#pragma unroll
      for (int mi = 0; mi < 4; ++mi)
#pragma unroll
        for (int ni = 0; ni < 4; ++ni)
#pragma unroll
          for (int r = 0; r < 4; ++r) {
            int lrow = mi * 16 + fq * 4 + r;
            int lcol = wc * 64 + ni * 16 + fr;
            int pc = lcol ^ ((lrow & 7) << 4);
            epi[lrow * 128 + pc] = acc[mi][ni][r];
          }
    }
    __syncthreads();
#pragma unroll
    for (int k = 0; k < 8; ++k) {
      int chunk = k * 256 + tid;
      int lrow = chunk >> 5;
      int c4 = (chunk & 31) * 4;
      int pc4 = c4 ^ ((lrow & 7) << 4);
      f32x4 v = *(f32x4*)&epi[lrow * 128 + pc4];
      int row = bm * BM + p * 64 + lrow;
      if constexpr (EPI == 1 || EPI == 4) {
        *(f32x4*)&((float*)Cv)[(size_t)ks * M * N + (size_t)row * N + bn * BN +
                               c4] = v;
      } else {  // EPI == 3
        if (row < mv)
          *(f32x4*)&((float*)Cv)[(size_t)glob[row] * N + bn * BN + c4] = v;
      }
    }
  }
}

// ---------- MFMA attention (compact positions, sums 4 q partials) ----------
__global__ __launch_bounds__(256) void attn5(
    const float* __restrict__ qc, const unsigned short* __restrict__ Kh,
    const unsigned short* __restrict__ Kl, const unsigned short* __restrict__ Vt,
    const int* __restrict__ cnt, const int* __restrict__ offs,
    unsigned short* __restrict__ attnc) {
  __shared__ unsigned short Pl[4][32][72];
  int tid = threadIdx.x, wid = tid >> 6, lane = tid & 63;
  int fr = lane & 15, fq = lane >> 4;
  int bt = blockIdx.x >> 6, rt = blockIdx.x & 63;
  int n = cnt[bt];
  int rbase = rt * 32;
  if (rbase >= n) return;
  int qbase = offs[bt] + rbase;

#pragma unroll 1
  for (int hp = 0; hp < 2; ++hp) {
    int h = wid * 2 + hp;
    const unsigned short* khb = Kh + ((size_t)(bt * 8 + h) * 64) * 64;
    const unsigned short* klb = Kl + ((size_t)(bt * 8 + h) * 64) * 64;
    const unsigned short* vtb = Vt + ((size_t)(bt * 8 + h) * 64) * 64;

    f32x4 sacc[2][4];
#pragma unroll
    for (int i = 0; i < 2; ++i)
#pragma unroll
      for (int j = 0; j < 4; ++j) sacc[i][j] = (f32x4){0.f, 0.f, 0.f, 0.f};

#pragma unroll
    for (int kk = 0; kk < 2; ++kk) {
      bf16x8 qh[2], ql[2];
#pragma unroll
      for (int mi = 0; mi < 2; ++mi) {
        size_t qo = (size_t)(qbase + mi * 16 + fr) * 512 + h * 64 + kk * 32 + fq * 8;
        f32x4 s0 = *(const f32x4*)(qc + qo);
        f32x4 s1 = *(const f32x4*)(qc + qo + 4);
#pragma unroll
        for (int sl = 1; sl < 4; ++sl) {
          s0 += *(const f32x4*)(qc + sl * QSTR + qo);
          s1 += *(const f32x4*)(qc + sl * QSTR + qo + 4);
        }
        float sv[8];
        *(f32x4*)&sv[0] = s0;
        *(f32x4*)&sv[4] = s1;
#pragma unroll
        for (int j = 0; j < 8; ++j) {
          unsigned short hi = f2bf(sv[j]);
          qh[mi][j] = (short)hi;
          ql[mi][j] = (short)f2bf(sv[j] - bf2f(hi));
        }
      }
#pragma unroll
      for (int ni = 0; ni < 4; ++ni) {
        size_t ko = (size_t)(ni * 16 + fr) * 64 + kk * 32 + fq * 8;
        bf16x8 kh = *(const bf16x8*)(khb + ko);
        bf16x8 kl = *(const bf16x8*)(klb + ko);
#pragma unroll
        for (int mi = 0; mi < 2; ++mi) {
          sacc[mi][ni] = __builtin_amdgcn_mfma_f32_16x16x32_bf16(
              qh[mi], kh, sacc[mi][ni], 0, 0, 0);
          sacc[mi][ni] = __builtin_amdgcn_mfma_f32_16x16x32_bf16(
              qh[mi], kl, sacc[mi][ni], 0, 0, 0);
          sacc[mi][ni] = __builtin_amdgcn_mfma_f32_16x16x32_bf16(
              ql[mi], kh, sacc[mi][ni], 0, 0, 0);
        }
      }
    }

#pragma unroll
    for (int mi = 0; mi < 2; ++mi) {
#pragma unroll
      for (int r = 0; r < 4; ++r) {
        float m = fmaxf(fmaxf(sacc[mi][0][r], sacc[mi][1][r]),
                        fmaxf(sacc[mi][2][r], sacc[mi][3][r]));
#pragma unroll
        for (int o = 1; o < 16; o <<= 1) m = fmaxf(m, __shfl_xor(m, o));
        float e0 = __expf(sacc[mi][0][r] - m);
        float e1 = __expf(sacc[mi][1][r] - m);
        float e2 = __expf(sacc[mi][2][r] - m);
        float e3 = __expf(sacc[mi][3][r] - m);
        float s = e0 + e1 + e2 + e3;
#pragma unroll
        for (int o = 1; o < 16; o <<= 1) s += __shfl_xor(s, o);
        float inv = 1.f / s;
        int row = mi * 16 + fq * 4 + r;
        Pl[wid][row][fr] = f2bf(e0 * inv);
        Pl[wid][row][16 + fr] = f2bf(e1 * inv);
        Pl[wid][row][32 + fr] = f2bf(e2 * inv);
        Pl[wid][row][48 + fr] = f2bf(e3 * inv);
      }
    }

    f32x4 oacc[2][4];
#pragma unroll
    for (int i = 0; i < 2; ++i)
#pragma unroll
      for (int j = 0; j < 4; ++j) oacc[i][j] = (f32x4){0.f, 0.f, 0.f, 0.f};
#pragma unroll
    for (int kk = 0; kk < 2; ++kk) {
      bf16x8 pa[2];
#pragma unroll
      for (int mi = 0; mi < 2; ++mi)
        pa[mi] = *(const bf16x8*)&Pl[wid][mi * 16 + fr][kk * 32 + fq * 8];
#pragma unroll
      for (int ni = 0; ni < 4; ++ni) {
        bf16x8 vb = *(const bf16x8*)(vtb + (size_t)(ni * 16 + fr) * 64 +
                                     kk * 32 + fq * 8);
#pragma unroll
        for (int mi = 0; mi < 2; ++mi)
          oacc[mi][ni] = __builtin_amdgcn_mfma_f32_16x16x32_bf16(
              pa[mi], vb, oacc[mi][ni], 0, 0, 0);
      }
    }

#pragma unroll
    for (int mi = 0; mi < 2; ++mi)
#pragma unroll
      for (int r = 0; r < 4; ++r) {
        int row = mi * 16 + fq * 4 + r;
        if (rbase + row < n) {
          unsigned short* ar = attnc + (size_t)(qbase + row) * 512 + h * 64 + fr;
          ar[0] = f2bf(oacc[mi][0][r]);
          ar[16] = f2bf(oacc[mi][1][r]);
          ar[32] = f2bf(oacc[mi][2][r]);
          ar[48] = f2bf(oacc[mi][3][r]);
        }
      }
  }
}

// ---------- launch ----------
extern "C" void kernel_launch(void* const* d_in, const int* in_sizes, int n_in,
                              void* d_out, int out_size, void* d_ws,
                              size_t ws_size, hipStream_t stream) {
  const float* latent = (const float*)d_in[0];
  const float* y = (const float*)d_in[1];
  const int* mask = (const int*)d_in[2];
  const float* W_vk = (const float*)d_in[3];
  const float* W_q = (const float*)d_in[4];
  const float* W_out = (const float*)d_in[5];
  float* out = (float*)d_out;

  char* ws = (char*)d_ws;
  size_t off = 0;
  auto alloc = [&](size_t bytes) -> void* {
    void* p = ws + off;
    off = (off + bytes + 255) & ~(size_t)255;
    return p;
  };
  unsigned short* WqT_h = (unsigned short*)alloc((size_t)512 * 4096 * 2);
  unsigned short* WqT_l = (unsigned short*)alloc((size_t)512 * 4096 * 2);
  unsigned short* WvkT_h = (unsigned short*)alloc((size_t)1024 * 2048 * 2);
  unsigned short* WvkT_l = (unsigned short*)alloc((size_t)1024 * 2048 * 2);
  unsigned short* WoT_h = (unsigned short*)alloc((size_t)4096 * 512 * 2);
  unsigned short* WoT_l = (unsigned short*)alloc((size_t)4096 * 512 * 2);
  unsigned short* ybf = (unsigned short*)alloc((size_t)8192 * 4096 * 2);
  unsigned short* latbf = (unsigned short*)alloc((size_t)768 * 2048 * 2);
  float* qc = (float*)alloc((size_t)4 * QCAP * 512 * 4);  // 4 split-K slices
  float* kvp = qc;  // kv partials alias qc (dead before q-GEMM writes qc)
  unsigned short* Khb = (unsigned short*)alloc((size_t)768 * 512 * 2);
  unsigned short* Klb = (unsigned short*)alloc((size_t)768 * 512 * 2);
  unsigned short* Vtb = (unsigned short*)alloc((size_t)768 * 512 * 2);
  unsigned short* attnc = (unsigned short*)alloc((size_t)8192 * 512 * 2);
  int* cnt = (int*)alloc(12 * 4);
  int* idx = (int*)alloc((size_t)12 * 2048 * 4);
  int* offs = (int*)alloc(13 * 4);
  int* glob = (int*)alloc(8192 * 4);
  int* mcnt = (int*)alloc(4);
  int* mlist = (int*)alloc(8192 * 4);

  hipMemsetAsync(cnt, 0, 12 * 4, stream);
  hipMemsetAsync(mcnt, 0, 4, stream);
  hipMemsetAsync(glob, 0, 8192 * 4, stream);

  cvt_bf16<<<768, 256, 0, stream>>>(latent, latbf, (long)768 * 2048);

  transpose_split3<<<6144, 256, 0, stream>>>(W_q, W_vk, W_out, WqT_h, WqT_l,
                                             WvkT_h, WvkT_l, WoT_h, WoT_l);

  gather_rows<<<32, 256, 0, stream>>>(mask, cnt, idx, mcnt, mlist);
  scan_build<<<12, 256, 0, stream>>>(cnt, offs, idx, glob);
  zerofill<<<2048, 256, 0, stream>>>(mcnt, mlist, out);

  cvt_gather<<<16384, 256, 0, stream>>>(y, glob, offs, ybf);

  // kv = latent[768,2048] @ W_vk -> 4 fp32 partial slices
  gemm2<4, 4, true><<<(768 / BM) * (1024 / BN) * 4, 256, 0, stream>>>(
      latbf, WvkT_h, WvkT_l, kvp, nullptr, nullptr, 768, 1024, 2048);
  kv_finish<<<768, 256, 0, stream>>>(kvp, Khb, Klb, Vtb);
  // q = ybf[compact,4096] @ W_q (single-bf16 B) -> 4 fp32 split-K slices
  gemm2<1, 4, false><<<(8192 / BM) * (512 / BN) * 4, 256, 0, stream>>>(
      ybf, WqT_h, nullptr, qc, nullptr, offs, QCAP, 512, 4096);
  // MFMA attention (sums 4 q partials)
  attn5<<<12 * 64, 256, 0, stream>>>(qc, Khb, Klb, Vtb, cnt, offs, attnc);
  // out = attnc[compact,512] @ W_out (single-bf16 B) -> scatter fp32 rows
  gemm2<3, 1, false><<<(8192 / BM) * (4096 / BN), 256, 0, stream>>>(
      attnc, WoT_h, nullptr, out, glob, offs, 8192, 4096, 512);
}